// Round 9
// baseline (3575.606 us; speedup 1.0000x reference)
//
#include <hip/hip_runtime.h>
#include <math.h>

#define LTOK 2080
#define DIM 128
#define NH 4
#define W0C 52
#define HFI 160
#define WFI 208
#define NPIX (HFI*WFI)   // 33280
#define CFCH 32
#define NSPLIT2 3
#define QBLK 64
#define NQB 33           // ceil(2080/64)
#define PSTRIDE2 2112    // 64*32 acc + 64 l

// ---------------- transpose (C,L) -> (L,C), batched over 2 images ----------------
__global__ __launch_bounds__(256) void transpose_b_kernel(const float* __restrict__ in0,
                                                          const float* __restrict__ in1,
                                                          float* __restrict__ out0,
                                                          float* __restrict__ out1)
{
    const float* in = blockIdx.z ? in1 : in0;
    float* out = blockIdx.z ? out1 : out0;
    __shared__ float T[32][33];
    int l0 = blockIdx.x * 32, c0 = blockIdx.y * 32;
    int t = threadIdx.x;
    #pragma unroll
    for (int e = 0; e < 4; ++e) {
        int idx = t + e * 256; int i = idx >> 5, j = idx & 31;
        T[i][j] = in[(size_t)(c0 + i) * LTOK + l0 + j];
    }
    __syncthreads();
    #pragma unroll
    for (int e = 0; e < 4; ++e) {
        int idx = t + e * 256; int j2 = idx >> 5, i2 = idx & 31;
        out[(size_t)(l0 + j2) * DIM + c0 + i2] = T[i2][j2];
    }
}

// ---------------- batched GEMM: Cz = Az(MxK) * B(NxK)^T + bias, z = image ----------------
__global__ __launch_bounds__(256) void gemm_nt_b2_kernel(const float* __restrict__ A0,
                                                         const float* __restrict__ A1, int lda,
                                                         const float* __restrict__ B, int ldb,
                                                         float* __restrict__ C0,
                                                         float* __restrict__ C1, int ldc,
                                                         int K,
                                                         const float* __restrict__ bias, int relu)
{
    const float* A = blockIdx.z ? A1 : A0;
    float* C = blockIdx.z ? C1 : C0;
    __shared__ float As[32][33];
    __shared__ float Bs[32][33];
    int tid = threadIdx.x;
    int n0 = blockIdx.x * 32, m0 = blockIdx.y * 32;
    int c = tid & 31, r8 = tid >> 5;
    float acc[4] = {0.f, 0.f, 0.f, 0.f};
    for (int k0 = 0; k0 < K; k0 += 32) {
        #pragma unroll
        for (int e = 0; e < 4; ++e) {
            int l = tid + e * 256;
            int i = l >> 5, k = l & 31;
            As[k][i] = A[(size_t)(m0 + i) * lda + k0 + k];
            Bs[k][i] = B[(size_t)(n0 + i) * ldb + k0 + k];
        }
        __syncthreads();
        #pragma unroll
        for (int k = 0; k < 32; ++k) {
            float bv = Bs[k][c];
            #pragma unroll
            for (int jj = 0; jj < 4; ++jj)
                acc[jj] += As[k][4 * r8 + jj] * bv;
        }
        __syncthreads();
    }
    #pragma unroll
    for (int jj = 0; jj < 4; ++jj) {
        float v = acc[jj];
        if (bias) v += bias[n0 + c];
        if (relu) v = fmaxf(v, 0.f);
        C[(size_t)(m0 + 4 * r8 + jj) * ldc + n0 + c] = v;
    }
}

// ---------------- score GEMM + fused softmax-stat partials ----------------
__global__ __launch_bounds__(256) void gemm_score_kernel(const float* __restrict__ A,
                                                         const float* __restrict__ B,
                                                         float* __restrict__ C,
                                                         float2* __restrict__ prs,
                                                         float2* __restrict__ pcs)
{
    __shared__ float As[32][33];
    __shared__ float Bs[32][33];
    __shared__ float cmS[8][32];
    __shared__ float ceS[8][32];
    int tid = threadIdx.x;
    int n0 = blockIdx.x * 32, m0 = blockIdx.y * 32;
    int c = tid & 31, r8 = tid >> 5;
    float acc[4] = {0.f, 0.f, 0.f, 0.f};
    for (int k0 = 0; k0 < 128; k0 += 32) {
        #pragma unroll
        for (int e = 0; e < 4; ++e) {
            int l = tid + e * 256;
            int i = l >> 5, k = l & 31;
            As[k][i] = A[(size_t)(m0 + i) * 128 + k0 + k];
            Bs[k][i] = B[(size_t)(n0 + i) * 128 + k0 + k];
        }
        __syncthreads();
        #pragma unroll
        for (int k = 0; k < 32; ++k) {
            float bv = Bs[k][c];
            #pragma unroll
            for (int jj = 0; jj < 4; ++jj)
                acc[jj] += As[k][4 * r8 + jj] * bv;
        }
        __syncthreads();
    }
    float v[4];
    #pragma unroll
    for (int jj = 0; jj < 4; ++jj) {
        v[jj] = 10.f * acc[jj];
        C[(size_t)(m0 + 4 * r8 + jj) * LTOK + n0 + c] = v[jj];
    }
    #pragma unroll
    for (int jj = 0; jj < 4; ++jj) {
        float m = v[jj];
        #pragma unroll
        for (int mm = 16; mm >= 1; mm >>= 1) m = fmaxf(m, __shfl_xor(m, mm, 32));
        float e = __expf(v[jj] - m);
        #pragma unroll
        for (int mm = 16; mm >= 1; mm >>= 1) e += __shfl_xor(e, mm, 32);
        if (c == 0) prs[(size_t)blockIdx.x * LTOK + m0 + 4 * r8 + jj] = make_float2(m, e);
    }
    float cmx = fmaxf(fmaxf(v[0], v[1]), fmaxf(v[2], v[3]));
    float cex = __expf(v[0] - cmx) + __expf(v[1] - cmx) + __expf(v[2] - cmx) + __expf(v[3] - cmx);
    cmS[r8][c] = cmx; ceS[r8][c] = cex;
    __syncthreads();
    if (r8 == 0) {
        float M = cmS[0][c], S = ceS[0][c];
        #pragma unroll
        for (int k = 1; k < 8; ++k) {
            float m2 = cmS[k][c], s2 = ceS[k][c];
            if (m2 > M) { S = S * __expf(M - m2) + s2; M = m2; }
            else        { S += s2 * __expf(m2 - M); }
        }
        pcs[(size_t)blockIdx.y * LTOK + n0 + c] = make_float2(M, S);
    }
}

// ---------------- merge 65 stat partials per row/col; store max + 1/sum ----------------
__global__ __launch_bounds__(256) void stats_combine_kernel(const float2* __restrict__ prs,
                                                            const float2* __restrict__ pcs,
                                                            float* __restrict__ rowmax,
                                                            float* __restrict__ rsinv,
                                                            float* __restrict__ colmax,
                                                            float* __restrict__ csinv)
{
    int id = blockIdx.x * 256 + threadIdx.x;
    if (id >= 2 * LTOK) return;
    const float2* p = (id < LTOK) ? (prs + id) : (pcs + (id - LTOK));
    float M = -1e30f;
    for (int i = 0; i < 65; ++i) M = fmaxf(M, p[(size_t)i * LTOK].x);
    float S = 0.f;
    for (int i = 0; i < 65; ++i) {
        float2 f = p[(size_t)i * LTOK];
        S += f.y * __expf(f.x - M);
    }
    if (id < LTOK) { rowmax[id] = M; rsinv[id] = 1.f / S; }
    else           { colmax[id - LTOK] = M; csinv[id - LTOK] = 1.f / S; }
}

// ---------------- P = exp(2S-rm-cm)*rsinv*csinv (in place) + argmax partials ----------------
__global__ __launch_bounds__(256) void dualp_argmax_kernel(float* __restrict__ S,
                                                           const float* __restrict__ rm,
                                                           const float* __restrict__ rsinv,
                                                           const float* __restrict__ cm,
                                                           const float* __restrict__ csinv,
                                                           float* __restrict__ prv,
                                                           int* __restrict__ pri,
                                                           float* __restrict__ pcv,
                                                           int* __restrict__ pci)
{
    __shared__ float cvS[8][32];
    __shared__ int   ciS[8][32];
    int tid = threadIdx.x;
    int n0 = blockIdx.x * 32, m0 = blockIdx.y * 32;
    int c = tid & 31, r8 = tid >> 5;
    int col = n0 + c;
    float cmv = cm[col], csv = csinv[col];
    float p[4];
    #pragma unroll
    for (int jj = 0; jj < 4; ++jj) {
        int row = m0 + 4 * r8 + jj;
        size_t o = (size_t)row * LTOK + col;
        float s = S[o];
        float pv = __expf(2.f * s - rm[row] - cmv) * (rsinv[row] * csv);
        S[o] = pv;
        p[jj] = pv;
    }
    #pragma unroll
    for (int jj = 0; jj < 4; ++jj) {
        float bv = p[jj]; int bi = col;
        #pragma unroll
        for (int mm = 16; mm >= 1; mm >>= 1) {
            float ov = __shfl_xor(bv, mm, 32);
            int   oi = __shfl_xor(bi, mm, 32);
            if (ov > bv || (ov == bv && oi < bi)) { bv = ov; bi = oi; }
        }
        if (c == 0) {
            prv[(size_t)blockIdx.x * LTOK + m0 + 4 * r8 + jj] = bv;
            pri[(size_t)blockIdx.x * LTOK + m0 + 4 * r8 + jj] = bi;
        }
    }
    float bv = p[0]; int bi = m0 + 4 * r8;
    #pragma unroll
    for (int jj = 1; jj < 4; ++jj)
        if (p[jj] > bv) { bv = p[jj]; bi = m0 + 4 * r8 + jj; }
    cvS[r8][c] = bv; ciS[r8][c] = bi;
    __syncthreads();
    if (r8 == 0) {
        #pragma unroll
        for (int k = 1; k < 8; ++k)
            if (cvS[k][c] > bv) { bv = cvS[k][c]; bi = ciS[k][c]; }
        pcv[(size_t)blockIdx.y * LTOK + col] = bv;
        pci[(size_t)blockIdx.y * LTOK + col] = bi;
    }
}

// ---------------- merge 65 argmax partials ----------------
__global__ __launch_bounds__(256) void argmax_combine_kernel(const float* __restrict__ prv,
                                                             const int* __restrict__ pri,
                                                             const float* __restrict__ pcv,
                                                             const int* __restrict__ pci,
                                                             int* __restrict__ idx0,
                                                             float* __restrict__ conf,
                                                             int* __restrict__ idx1)
{
    int id = blockIdx.x * 256 + threadIdx.x;
    if (id >= 2 * LTOK) return;
    if (id < LTOK) {
        float best = -1e30f; int bi = 0;
        for (int i = 0; i < 65; ++i) {
            float v = prv[(size_t)i * LTOK + id];
            if (v > best) { best = v; bi = pri[(size_t)i * LTOK + id]; }
        }
        idx0[id] = bi; conf[id] = best;
    } else {
        int colI = id - LTOK;
        float best = -1e30f; int bi = 0;
        for (int i = 0; i < 65; ++i) {
            float v = pcv[(size_t)i * LTOK + colI];
            if (v > best) { best = v; bi = pci[(size_t)i * LTOK + colI]; }
        }
        idx1[colI] = bi;
    }
}

// ---------------- MHA partial v2: 64-row Q tile, 4x4 register-blocked score,
//                  4x2 register-blocked PV. blockIdx.y encodes (img,h). ----------------
__global__ __launch_bounds__(256, 3) void mha_partial2_kernel(const float* __restrict__ qkvA,
                                                              const float* __restrict__ qkvB,
                                                              int cross,
                                                              float* __restrict__ part)
{
    __shared__ float Qs[QBLK][36];
    __shared__ float Ks[64][36];
    __shared__ float Vt[32][68];
    __shared__ float Ps[QBLK][68];
    int tid = threadIdx.x;
    int qb = blockIdx.x, ns = blockIdx.z;
    int img = blockIdx.y >> 2, h = blockIdx.y & 3;
    const float* qsrc  = img ? qkvB : qkvA;
    const float* kvsrc = cross ? (img ? qkvA : qkvB) : qsrc;
    int c4 = tid & 15;          // col-thread / d-col base
    int rg = tid >> 4;          // row-group 0..15 -> rows rg*4..rg*4+3
    const float sc = 0.17677669529663687f; // 1/sqrt(32)

    // ---- stage Q (64x32), rows clamped at 2079 (outputs for clamped rows unread) ----
    {
        int r = tid >> 2, d8 = (tid & 3) << 3;
        int qr = qb * QBLK + r; qr = qr < LTOK ? qr : (LTOK - 1);
        const float* src = qsrc + (size_t)qr * 384 + h * 32 + d8;
        *(float4*)(&Qs[r][d8])     = *(const float4*)(src);
        *(float4*)(&Qs[r][d8 + 4]) = *(const float4*)(src + 4);
    }
    float acc[4][2] = {{0.f,0.f},{0.f,0.f},{0.f,0.f},{0.f,0.f}};
    float lacc[4] = {0.f, 0.f, 0.f, 0.f};
    __syncthreads();

    const int koff = 128 + h * 32, voff = 256 + h * 32;
    for (int t = ns; t < 33; t += NSPLIT2) {
        int j0 = t * 64;
        // ---- stage K (64x32) and V transposed (32x64) ----
        {
            int r = tid >> 3, d4 = (tid & 7) << 2;
            int j1 = j0 + r, j2 = j0 + r + 32;
            float4 k1 = *(const float4*)(kvsrc + (size_t)j1 * 384 + koff + d4);
            float4 v1 = *(const float4*)(kvsrc + (size_t)j1 * 384 + voff + d4);
            float4 k2 = make_float4(0.f, 0.f, 0.f, 0.f);
            float4 v2 = make_float4(0.f, 0.f, 0.f, 0.f);
            if (j2 < LTOK) {
                k2 = *(const float4*)(kvsrc + (size_t)j2 * 384 + koff + d4);
                v2 = *(const float4*)(kvsrc + (size_t)j2 * 384 + voff + d4);
            }
            *(float4*)(&Ks[r][d4])      = k1;
            *(float4*)(&Ks[r + 32][d4]) = k2;
            Vt[d4 + 0][r] = v1.x; Vt[d4 + 1][r] = v1.y; Vt[d4 + 2][r] = v1.z; Vt[d4 + 3][r] = v1.w;
            Vt[d4 + 0][r + 32] = v2.x; Vt[d4 + 1][r + 32] = v2.y; Vt[d4 + 2][r + 32] = v2.z; Vt[d4 + 3][r + 32] = v2.w;
        }
        __syncthreads();
        // ---- score 4x4: rows rg*4+jj, cols j0 + k*16 + c4 ----
        float s[4][4] = {{0.f,0.f,0.f,0.f},{0.f,0.f,0.f,0.f},{0.f,0.f,0.f,0.f},{0.f,0.f,0.f,0.f}};
        #pragma unroll
        for (int d4 = 0; d4 < 8; ++d4) {
            float4 kf[4];
            #pragma unroll
            for (int k = 0; k < 4; ++k) kf[k] = *(const float4*)(&Ks[k * 16 + c4][d4 << 2]);
            #pragma unroll
            for (int jj = 0; jj < 4; ++jj) {
                float4 q = *(const float4*)(&Qs[rg * 4 + jj][d4 << 2]);
                #pragma unroll
                for (int k = 0; k < 4; ++k)
                    s[jj][k] += q.x * kf[k].x + q.y * kf[k].y + q.z * kf[k].z + q.w * kf[k].w;
            }
        }
        // ---- exp + Ps store + row-sum ----
        #pragma unroll
        for (int jj = 0; jj < 4; ++jj) {
            float4 pv;
            float* pp = (float*)&pv;
            #pragma unroll
            for (int k = 0; k < 4; ++k) {
                bool ok = (j0 + k * 16 + c4) < LTOK;
                pp[k] = ok ? __expf(s[jj][k] * sc) : 0.f;
                lacc[jj] += pp[k];
            }
            // store the 4 cols (strided by 16) as scalars: cols k*16+c4
            Ps[rg * 4 + jj][c4]      = pv.x;
            Ps[rg * 4 + jj][c4 + 16] = pv.y;
            Ps[rg * 4 + jj][c4 + 32] = pv.z;
            Ps[rg * 4 + jj][c4 + 48] = pv.w;
        }
        __syncthreads();
        // ---- PV 4x2: acc[jj][cc] += sum_j Ps[rg*4+jj][j] * Vt[c4+cc*16][j] ----
        #pragma unroll
        for (int j4 = 0; j4 < 16; ++j4) {
            float4 v0 = *(const float4*)(&Vt[c4][j4 << 2]);
            float4 v1 = *(const float4*)(&Vt[c4 + 16][j4 << 2]);
            #pragma unroll
            for (int jj = 0; jj < 4; ++jj) {
                float4 pq = *(const float4*)(&Ps[rg * 4 + jj][j4 << 2]);
                acc[jj][0] += pq.x * v0.x + pq.y * v0.y + pq.z * v0.z + pq.w * v0.w;
                acc[jj][1] += pq.x * v1.x + pq.y * v1.y + pq.z * v1.z + pq.w * v1.w;
            }
        }
        __syncthreads();
    }
    // ---- store partial: 64x32 acc + 64 l ----
    float* pb = part + (size_t)((((size_t)img * NQB + qb) * NH + h) * NSPLIT2 + ns) * PSTRIDE2;
    #pragma unroll
    for (int jj = 0; jj < 4; ++jj) {
        int row = rg * 4 + jj;
        pb[row * 32 + c4]      = acc[jj][0];
        pb[row * 32 + c4 + 16] = acc[jj][1];
    }
    #pragma unroll
    for (int jj = 0; jj < 4; ++jj) {
        float l = lacc[jj];
        #pragma unroll
        for (int mm = 8; mm >= 1; mm >>= 1) l += __shfl_xor(l, mm, 16);
        if (c4 == 0) pb[2048 + rg * 4 + jj] = l;
    }
}

// ---------------- MHA combine v2: grid (33, 8) ----------------
__global__ __launch_bounds__(256) void mha_combine2_kernel(const float* __restrict__ part,
                                                           float* __restrict__ out0,
                                                           float* __restrict__ out1)
{
    int tid = threadIdx.x;
    int qb = blockIdx.x;
    int img = blockIdx.y >> 2, h = blockIdx.y & 3;
    float* out = img ? out1 : out0;
    int c = tid & 31, rg8 = tid >> 5;      // 8 groups x 8 rows
    const float* pb = part + (size_t)(((size_t)img * NQB + qb) * NH + h) * NSPLIT2 * PSTRIDE2;
    #pragma unroll
    for (int jj = 0; jj < 8; ++jj) {
        int row = rg8 * 8 + jj;
        int qrow = qb * QBLK + row;
        if (qrow >= LTOK) continue;
        float num = 0.f, den = 0.f;
        #pragma unroll
        for (int ns = 0; ns < NSPLIT2; ++ns) {
            num += pb[ns * PSTRIDE2 + row * 32 + c];
            den += pb[ns * PSTRIDE2 + 2048 + row];
        }
        out[(size_t)qrow * DIM + h * 32 + c] = num / den;
    }
}

// ---------------- residual add + LayerNorm (in place), batched ----------------
__global__ __launch_bounds__(256) void addln_b_kernel(float* __restrict__ f0,
                                                      float* __restrict__ f1,
                                                      const float* __restrict__ t0,
                                                      const float* __restrict__ t1,
                                                      const float* __restrict__ g,
                                                      const float* __restrict__ b)
{
    float* f = blockIdx.y ? f1 : f0;
    const float* t = blockIdx.y ? t1 : t0;
    int row = blockIdx.x * 4 + (threadIdx.x >> 6);
    int lane = threadIdx.x & 63;
    size_t base = (size_t)row * DIM;
    float x0 = f[base + lane] + t[base + lane];
    float x1 = f[base + lane + 64] + t[base + lane + 64];
    float s = x0 + x1;
    #pragma unroll
    for (int mm = 32; mm >= 1; mm >>= 1) s += __shfl_xor(s, mm, 64);
    float mean = s * (1.f / 128.f);
    float d0 = x0 - mean, d1 = x1 - mean;
    float v = d0 * d0 + d1 * d1;
    #pragma unroll
    for (int mm = 32; mm >= 1; mm >>= 1) v += __shfl_xor(v, mm, 64);
    float rstd = rsqrtf(v * (1.f / 128.f) + 1e-5f);
    f[base + lane]      = d0 * rstd * g[lane] + b[lane];
    f[base + lane + 64] = d1 * rstd * g[lane + 64] + b[lane + 64];
}

// ---------------- L2-normalize rows, batched ----------------
__global__ __launch_bounds__(256) void normrows_b_kernel(const float* __restrict__ i0,
                                                         const float* __restrict__ i1,
                                                         float* __restrict__ o0,
                                                         float* __restrict__ o1)
{
    const float* f = blockIdx.y ? i1 : i0;
    float* o = blockIdx.y ? o1 : o0;
    int row = blockIdx.x * 4 + (threadIdx.x >> 6);
    int lane = threadIdx.x & 63;
    size_t base = (size_t)row * DIM;
    float x0 = f[base + lane], x1 = f[base + lane + 64];
    float v = x0 * x0 + x1 * x1;
    #pragma unroll
    for (int mm = 32; mm >= 1; mm >>= 1) v += __shfl_xor(v, mm, 64);
    float inv = 1.f / fmaxf(sqrtf(v), 1e-12f);
    o[base + lane] = x0 * inv;
    o[base + lane + 64] = x1 * inv;
}

// ---------------- match outputs: valid, conf, pt0 ----------------
__global__ __launch_bounds__(256) void match_kernel(const int* __restrict__ idx0,
                                                    const int* __restrict__ idx1,
                                                    const float* __restrict__ conf,
                                                    float* __restrict__ out_valid,
                                                    float* __restrict__ out_conf,
                                                    float* __restrict__ out_pt0)
{
    int i = blockIdx.x * 256 + threadIdx.x;
    if (i >= LTOK) return;
    int j = idx0[i];
    bool valid = (idx1[j] == i) && (conf[i] > 0.2f);
    out_valid[i] = valid ? 1.f : 0.f;
    out_conf[i] = conf[i];
    out_pt0[2 * i]     = (float)(i % W0C) * 8.f + 4.f;
    out_pt0[2 * i + 1] = (float)(i / W0C) * 8.f + 4.f;
}

// ---------------- fine projection, batched ----------------
__global__ __launch_bounds__(256) void fine_proj_b_kernel(const float* __restrict__ fin0,
                                                          const float* __restrict__ fin1,
                                                          const float* __restrict__ w,
                                                          const float* __restrict__ b,
                                                          float* __restrict__ fout0,
                                                          float* __restrict__ fout1)
{
    const float* fin = blockIdx.y ? fin1 : fin0;
    float* fout = blockIdx.y ? fout1 : fout0;
    __shared__ float ws_[32][32];
    __shared__ float bs[32];
    int t = threadIdx.x;
    #pragma unroll
    for (int e = 0; e < 4; ++e) { int l = t + e * 256; ws_[l >> 5][l & 31] = w[l]; }
    if (t < 32) bs[t] = b[t];
    __syncthreads();
    int p = blockIdx.x * 256 + t;
    if (p >= NPIX) return;
    float x[32];
    #pragma unroll
    for (int cc = 0; cc < 32; ++cc) x[cc] = fin[(size_t)cc * NPIX + p];
    #pragma unroll
    for (int o = 0; o < 32; ++o) {
        float a = bs[o];
        #pragma unroll
        for (int cc = 0; cc < 32; ++cc) a += ws_[o][cc] * x[cc];
        fout[(size_t)o * NPIX + p] = a;
    }
}

// ---------------- fine match ----------------
__global__ __launch_bounds__(64) void fine_match_kernel(const int* __restrict__ idx0,
                                                        const float* __restrict__ f0p,
                                                        const float* __restrict__ f1p,
                                                        float* __restrict__ out_pt1)
{
    int i = blockIdx.x;
    int l = threadIdx.x;
    int j = idx0[i];
    int m0x = i % W0C, m0y = i / W0C;
    int m1x = j % W0C, m1y = j / W0C;
    int c0x = m0x * 4, c0y = m0y * 4, c1x = m1x * 4, c1y = m1y * 4;
    bool inb = (c0x - 2 >= 0) && (c0x + 2 < WFI) && (c0y - 2 >= 0) && (c0y + 2 < HFI)
            && (c1x - 2 >= 0) && (c1x + 2 < WFI) && (c1y - 2 >= 0) && (c1y + 2 < HFI);
    int cy0 = min(max(c0y, 2), HFI - 3), cx0 = min(max(c0x, 2), WFI - 3);
    int cy1 = min(max(c1y, 2), HFI - 3), cx1 = min(max(c1x, 2), WFI - 3);
    int dy = l / 5 - 2, dx = l % 5 - 2;
    float corr = -1e30f;
    if (l < 25) {
        float a = 0.f;
        int p0 = cy0 * WFI + cx0;
        int p1 = (cy1 + dy) * WFI + (cx1 + dx);
        #pragma unroll
        for (int cc = 0; cc < 32; ++cc)
            a += f0p[(size_t)cc * NPIX + p0] * f1p[(size_t)cc * NPIX + p1];
        corr = a;
    }
    float mx = corr;
    #pragma unroll
    for (int mm = 32; mm >= 1; mm >>= 1) mx = fmaxf(mx, __shfl_xor(mx, mm, 64));
    float p = (l < 25) ? expf(corr - mx) : 0.f;
    float s = p, sx = p * (float)dx, sy = p * (float)dy;
    #pragma unroll
    for (int mm = 32; mm >= 1; mm >>= 1) {
        s  += __shfl_xor(s, mm, 64);
        sx += __shfl_xor(sx, mm, 64);
        sy += __shfl_xor(sy, mm, 64);
    }
    if (l == 0) {
        float offx = sx / s, offy = sy / s;
        float px = (float)m1x * 8.f + 4.f;
        float py = (float)m1y * 8.f + 4.f;
        if (inb) { px += offx * 2.f; py += offy * 2.f; }
        out_pt1[2 * i]     = px;
        out_pt1[2 * i + 1] = py;
    }
}

// ---------------- host launch ----------------
extern "C" void kernel_launch(void* const* d_in, const int* in_sizes, int n_in,
                              void* d_out, int out_size, void* d_ws, size_t ws_size,
                              hipStream_t stream) {
    (void)in_sizes; (void)n_in; (void)out_size; (void)ws_size;
    const float* coarse0 = (const float*)d_in[0];
    const float* coarse1 = (const float*)d_in[1];
    const float* fine0   = (const float*)d_in[2];
    const float* fine1   = (const float*)d_in[3];
    const float* sa_in_w  = (const float*)d_in[4];
    const float* sa_in_b  = (const float*)d_in[5];
    const float* sa_out_w = (const float*)d_in[6];
    const float* sa_out_b = (const float*)d_in[7];
    const float* ca_in_w  = (const float*)d_in[8];
    const float* ca_in_b  = (const float*)d_in[9];
    const float* ca_out_w = (const float*)d_in[10];
    const float* ca_out_b = (const float*)d_in[11];
    const float* sn_g = (const float*)d_in[12];
    const float* sn_b = (const float*)d_in[13];
    const float* cn_g = (const float*)d_in[14];
    const float* cn_b = (const float*)d_in[15];
    const float* ffn_w1 = (const float*)d_in[16];
    const float* ffn_b1 = (const float*)d_in[17];
    const float* ffn_w2 = (const float*)d_in[18];
    const float* ffn_b2 = (const float*)d_in[19];
    const float* fn_g = (const float*)d_in[20];
    const float* fn_b = (const float*)d_in[21];
    const float* proj_w = (const float*)d_in[22];
    const float* proj_b = (const float*)d_in[23];

    float* w = (float*)d_ws;
    float* f0   = w; w += (size_t)LTOK * DIM;
    float* f1   = w; w += (size_t)LTOK * DIM;
    float* qkv0 = w; w += (size_t)LTOK * 384;
    float* qkv1 = w; w += (size_t)LTOK * 384;
    float* att0 = w; w += (size_t)LTOK * DIM;
    float* att1 = w; w += (size_t)LTOK * DIM;
    float* tmp0 = w; w += (size_t)LTOK * DIM;
    float* tmp1 = w; w += (size_t)LTOK * DIM;
    float* f0n  = w; w += (size_t)LTOK * DIM;
    float* f1n  = w; w += (size_t)LTOK * DIM;
    // R1: time-shared — part (MHA) | hid0/hid1 (FFN) | f0p/f1p (fine)
    float* R1   = w; w += (size_t)2745600;
    float* rowmax = w; w += LTOK;
    float* rsinv  = w; w += LTOK;
    float* colmax = w; w += LTOK;
    float* csinv  = w; w += LTOK;
    float* conf   = w; w += LTOK;
    int* idx0 = (int*)w; w += LTOK;
    int* idx1 = (int*)w; w += LTOK;

    float* part = R1;   // 2*33*4*3*2112 = 1,672,704 floats
    float* hid0 = R1;
    float* hid1 = R1 + (size_t)LTOK * 256;
    float* f0p  = R1;
    float* f1p  = R1 + (size_t)CFCH * NPIX;

    // matching-tail partials alias the (dead after transformer loop) qkv buffers
    float2* prs = (float2*)qkv0;
    float2* pcs = (float2*)(qkv0 + 2 * 65 * LTOK);
    float*  prv = qkv1;
    int*    pri = (int*)(qkv1 + 65 * LTOK);
    float*  pcv = qkv1 + 2 * 65 * LTOK;
    int*    pci = (int*)(qkv1 + 3 * 65 * LTOK);

    float* Pout = (float*)d_out;
    float* out_valid = Pout + (size_t)LTOK * LTOK;
    float* out_conf  = out_valid + LTOK;
    float* out_pt0   = out_conf + LTOK;
    float* out_pt1   = out_pt0 + 2 * LTOK;

    dim3 b256(256);
    dim3 gMHA(NQB, 8, NSPLIT2);
    dim3 gCMB(NQB, 8);
    dim3 gLN(520, 2);
    transpose_b_kernel<<<dim3(65, 4, 2), b256, 0, stream>>>(coarse0, coarse1, f0, f1);

    for (int i = 0; i < 2; ++i) {
        const float* saw = sa_in_w + (size_t)i * 384 * 128;
        const float* sab = sa_in_b + (size_t)i * 384;
        const float* sow = sa_out_w + (size_t)i * 128 * 128;
        const float* sob = sa_out_b + (size_t)i * 128;
        const float* caw = ca_in_w + (size_t)i * 384 * 128;
        const float* cab = ca_in_b + (size_t)i * 384;
        const float* cow = ca_out_w + (size_t)i * 128 * 128;
        const float* cob = ca_out_b + (size_t)i * 128;
        const float* w1 = ffn_w1 + (size_t)i * 256 * 128;
        const float* b1 = ffn_b1 + (size_t)i * 256;
        const float* w2 = ffn_w2 + (size_t)i * 128 * 256;
        const float* b2 = ffn_b2 + (size_t)i * 128;

        // ---- self attention ----
        gemm_nt_b2_kernel<<<dim3(12, 65, 2), b256, 0, stream>>>(f0, f1, 128, saw, 128, qkv0, qkv1, 384, 128, sab, 0);
        mha_partial2_kernel<<<gMHA, b256, 0, stream>>>(qkv0, qkv1, 0, part);
        mha_combine2_kernel<<<gCMB, b256, 0, stream>>>(part, att0, att1);
        gemm_nt_b2_kernel<<<dim3(4, 65, 2), b256, 0, stream>>>(att0, att1, 128, sow, 128, tmp0, tmp1, 128, 128, sob, 0);
        addln_b_kernel<<<gLN, b256, 0, stream>>>(f0, f1, tmp0, tmp1, sn_g + (size_t)i * 128, sn_b + (size_t)i * 128);

        // ---- cross attention ----
        gemm_nt_b2_kernel<<<dim3(12, 65, 2), b256, 0, stream>>>(f0, f1, 128, caw, 128, qkv0, qkv1, 384, 128, cab, 0);
        mha_partial2_kernel<<<gMHA, b256, 0, stream>>>(qkv0, qkv1, 1, part);
        mha_combine2_kernel<<<gCMB, b256, 0, stream>>>(part, att0, att1);
        gemm_nt_b2_kernel<<<dim3(4, 65, 2), b256, 0, stream>>>(att0, att1, 128, cow, 128, tmp0, tmp1, 128, 128, cob, 0);
        addln_b_kernel<<<gLN, b256, 0, stream>>>(f0, f1, tmp0, tmp1, cn_g + (size_t)i * 128, cn_b + (size_t)i * 128);

        // ---- FFN ----
        gemm_nt_b2_kernel<<<dim3(8, 65, 2), b256, 0, stream>>>(f0, f1, 128, w1, 128, hid0, hid1, 256, 128, b1, 1);
        gemm_nt_b2_kernel<<<dim3(4, 65, 2), b256, 0, stream>>>(hid0, hid1, 256, w2, 256, tmp0, tmp1, 128, 256, b2, 0);
        addln_b_kernel<<<gLN, b256, 0, stream>>>(f0, f1, tmp0, tmp1, fn_g + (size_t)i * 128, fn_b + (size_t)i * 128);
    }

    // ---- matching (2 matrix passes total) ----
    normrows_b_kernel<<<gLN, b256, 0, stream>>>(f0, f1, f0n, f1n);
    gemm_score_kernel<<<dim3(65, 65), b256, 0, stream>>>(f0n, f1n, Pout, prs, pcs);
    stats_combine_kernel<<<17, b256, 0, stream>>>(prs, pcs, rowmax, rsinv, colmax, csinv);
    dualp_argmax_kernel<<<dim3(65, 65), b256, 0, stream>>>(Pout, rowmax, rsinv, colmax, csinv,
                                                           prv, pri, pcv, pci);
    argmax_combine_kernel<<<17, b256, 0, stream>>>(prv, pri, pcv, pci, idx0, conf, idx1);
    match_kernel<<<9, b256, 0, stream>>>(idx0, idx1, conf, out_valid, out_conf, out_pt0);

    // ---- fine refinement ----
    fine_proj_b_kernel<<<dim3(130, 2), b256, 0, stream>>>(fine0, fine1, proj_w, proj_b, f0p, f1p);
    fine_match_kernel<<<LTOK, dim3(64), 0, stream>>>(idx0, f0p, f1p, out_pt1);
}

// Round 10
// 926.433 us; speedup vs baseline: 3.8595x; 3.8595x over previous
//
#include <hip/hip_runtime.h>
#include <math.h>

#define LTOK 2080
#define DIM 128
#define NH 4
#define W0C 52
#define HFI 160
#define WFI 208
#define NPIX (HFI*WFI)   // 33280
#define CFCH 32
#define NSPLIT2 3
#define QBLK 64
#define NQB 33           // ceil(2080/64)
#define PSTRIDE2 2112    // 64*32 acc + 64 l

#define DOT4(q,k) ((q).x*(k).x + (q).y*(k).y + (q).z*(k).z + (q).w*(k).w)

// ---------------- transpose (C,L) -> (L,C), batched over 2 images ----------------
__global__ __launch_bounds__(256) void transpose_b_kernel(const float* __restrict__ in0,
                                                          const float* __restrict__ in1,
                                                          float* __restrict__ out0,
                                                          float* __restrict__ out1)
{
    const float* in = blockIdx.z ? in1 : in0;
    float* out = blockIdx.z ? out1 : out0;
    __shared__ float T[32][33];
    int l0 = blockIdx.x * 32, c0 = blockIdx.y * 32;
    int t = threadIdx.x;
    #pragma unroll
    for (int e = 0; e < 4; ++e) {
        int idx = t + e * 256; int i = idx >> 5, j = idx & 31;
        T[i][j] = in[(size_t)(c0 + i) * LTOK + l0 + j];
    }
    __syncthreads();
    #pragma unroll
    for (int e = 0; e < 4; ++e) {
        int idx = t + e * 256; int j2 = idx >> 5, i2 = idx & 31;
        out[(size_t)(l0 + j2) * DIM + c0 + i2] = T[i2][j2];
    }
}

// ---------------- batched GEMM: Cz = Az(MxK) * B(NxK)^T + bias, z = image ----------------
__global__ __launch_bounds__(256) void gemm_nt_b2_kernel(const float* __restrict__ A0,
                                                         const float* __restrict__ A1, int lda,
                                                         const float* __restrict__ B, int ldb,
                                                         float* __restrict__ C0,
                                                         float* __restrict__ C1, int ldc,
                                                         int K,
                                                         const float* __restrict__ bias, int relu)
{
    const float* A = blockIdx.z ? A1 : A0;
    float* C = blockIdx.z ? C1 : C0;
    __shared__ float As[32][33];
    __shared__ float Bs[32][33];
    int tid = threadIdx.x;
    int n0 = blockIdx.x * 32, m0 = blockIdx.y * 32;
    int c = tid & 31, r8 = tid >> 5;
    float acc[4] = {0.f, 0.f, 0.f, 0.f};
    for (int k0 = 0; k0 < K; k0 += 32) {
        #pragma unroll
        for (int e = 0; e < 4; ++e) {
            int l = tid + e * 256;
            int i = l >> 5, k = l & 31;
            As[k][i] = A[(size_t)(m0 + i) * lda + k0 + k];
            Bs[k][i] = B[(size_t)(n0 + i) * ldb + k0 + k];
        }
        __syncthreads();
        #pragma unroll
        for (int k = 0; k < 32; ++k) {
            float bv = Bs[k][c];
            #pragma unroll
            for (int jj = 0; jj < 4; ++jj)
                acc[jj] += As[k][4 * r8 + jj] * bv;
        }
        __syncthreads();
    }
    #pragma unroll
    for (int jj = 0; jj < 4; ++jj) {
        float v = acc[jj];
        if (bias) v += bias[n0 + c];
        if (relu) v = fmaxf(v, 0.f);
        C[(size_t)(m0 + 4 * r8 + jj) * ldc + n0 + c] = v;
    }
}

// ---------------- score GEMM + fused softmax-stat partials ----------------
__global__ __launch_bounds__(256) void gemm_score_kernel(const float* __restrict__ A,
                                                         const float* __restrict__ B,
                                                         float* __restrict__ C,
                                                         float2* __restrict__ prs,
                                                         float2* __restrict__ pcs)
{
    __shared__ float As[32][33];
    __shared__ float Bs[32][33];
    __shared__ float cmS[8][32];
    __shared__ float ceS[8][32];
    int tid = threadIdx.x;
    int n0 = blockIdx.x * 32, m0 = blockIdx.y * 32;
    int c = tid & 31, r8 = tid >> 5;
    float acc[4] = {0.f, 0.f, 0.f, 0.f};
    for (int k0 = 0; k0 < 128; k0 += 32) {
        #pragma unroll
        for (int e = 0; e < 4; ++e) {
            int l = tid + e * 256;
            int i = l >> 5, k = l & 31;
            As[k][i] = A[(size_t)(m0 + i) * 128 + k0 + k];
            Bs[k][i] = B[(size_t)(n0 + i) * 128 + k0 + k];
        }
        __syncthreads();
        #pragma unroll
        for (int k = 0; k < 32; ++k) {
            float bv = Bs[k][c];
            #pragma unroll
            for (int jj = 0; jj < 4; ++jj)
                acc[jj] += As[k][4 * r8 + jj] * bv;
        }
        __syncthreads();
    }
    float v[4];
    #pragma unroll
    for (int jj = 0; jj < 4; ++jj) {
        v[jj] = 10.f * acc[jj];
        C[(size_t)(m0 + 4 * r8 + jj) * LTOK + n0 + c] = v[jj];
    }
    #pragma unroll
    for (int jj = 0; jj < 4; ++jj) {
        float m = v[jj];
        #pragma unroll
        for (int mm = 16; mm >= 1; mm >>= 1) m = fmaxf(m, __shfl_xor(m, mm, 32));
        float e = __expf(v[jj] - m);
        #pragma unroll
        for (int mm = 16; mm >= 1; mm >>= 1) e += __shfl_xor(e, mm, 32);
        if (c == 0) prs[(size_t)blockIdx.x * LTOK + m0 + 4 * r8 + jj] = make_float2(m, e);
    }
    float cmx = fmaxf(fmaxf(v[0], v[1]), fmaxf(v[2], v[3]));
    float cex = __expf(v[0] - cmx) + __expf(v[1] - cmx) + __expf(v[2] - cmx) + __expf(v[3] - cmx);
    cmS[r8][c] = cmx; ceS[r8][c] = cex;
    __syncthreads();
    if (r8 == 0) {
        float M = cmS[0][c], S = ceS[0][c];
        #pragma unroll
        for (int k = 1; k < 8; ++k) {
            float m2 = cmS[k][c], s2 = ceS[k][c];
            if (m2 > M) { S = S * __expf(M - m2) + s2; M = m2; }
            else        { S += s2 * __expf(m2 - M); }
        }
        pcs[(size_t)blockIdx.y * LTOK + n0 + c] = make_float2(M, S);
    }
}

// ---------------- merge 65 stat partials per row/col; store max + 1/sum ----------------
__global__ __launch_bounds__(256) void stats_combine_kernel(const float2* __restrict__ prs,
                                                            const float2* __restrict__ pcs,
                                                            float* __restrict__ rowmax,
                                                            float* __restrict__ rsinv,
                                                            float* __restrict__ colmax,
                                                            float* __restrict__ csinv)
{
    int id = blockIdx.x * 256 + threadIdx.x;
    if (id >= 2 * LTOK) return;
    const float2* p = (id < LTOK) ? (prs + id) : (pcs + (id - LTOK));
    float M = -1e30f;
    for (int i = 0; i < 65; ++i) M = fmaxf(M, p[(size_t)i * LTOK].x);
    float S = 0.f;
    for (int i = 0; i < 65; ++i) {
        float2 f = p[(size_t)i * LTOK];
        S += f.y * __expf(f.x - M);
    }
    if (id < LTOK) { rowmax[id] = M; rsinv[id] = 1.f / S; }
    else           { colmax[id - LTOK] = M; csinv[id - LTOK] = 1.f / S; }
}

// ---------------- P = exp(2S-rm-cm)*rsinv*csinv (in place) + argmax partials ----------------
__global__ __launch_bounds__(256) void dualp_argmax_kernel(float* __restrict__ S,
                                                           const float* __restrict__ rm,
                                                           const float* __restrict__ rsinv,
                                                           const float* __restrict__ cm,
                                                           const float* __restrict__ csinv,
                                                           float* __restrict__ prv,
                                                           int* __restrict__ pri,
                                                           float* __restrict__ pcv,
                                                           int* __restrict__ pci)
{
    __shared__ float cvS[8][32];
    __shared__ int   ciS[8][32];
    int tid = threadIdx.x;
    int n0 = blockIdx.x * 32, m0 = blockIdx.y * 32;
    int c = tid & 31, r8 = tid >> 5;
    int col = n0 + c;
    float cmv = cm[col], csv = csinv[col];
    float p[4];
    #pragma unroll
    for (int jj = 0; jj < 4; ++jj) {
        int row = m0 + 4 * r8 + jj;
        size_t o = (size_t)row * LTOK + col;
        float s = S[o];
        float pv = __expf(2.f * s - rm[row] - cmv) * (rsinv[row] * csv);
        S[o] = pv;
        p[jj] = pv;
    }
    #pragma unroll
    for (int jj = 0; jj < 4; ++jj) {
        float bv = p[jj]; int bi = col;
        #pragma unroll
        for (int mm = 16; mm >= 1; mm >>= 1) {
            float ov = __shfl_xor(bv, mm, 32);
            int   oi = __shfl_xor(bi, mm, 32);
            if (ov > bv || (ov == bv && oi < bi)) { bv = ov; bi = oi; }
        }
        if (c == 0) {
            prv[(size_t)blockIdx.x * LTOK + m0 + 4 * r8 + jj] = bv;
            pri[(size_t)blockIdx.x * LTOK + m0 + 4 * r8 + jj] = bi;
        }
    }
    float bv = p[0]; int bi = m0 + 4 * r8;
    #pragma unroll
    for (int jj = 1; jj < 4; ++jj)
        if (p[jj] > bv) { bv = p[jj]; bi = m0 + 4 * r8 + jj; }
    cvS[r8][c] = bv; ciS[r8][c] = bi;
    __syncthreads();
    if (r8 == 0) {
        #pragma unroll
        for (int k = 1; k < 8; ++k)
            if (cvS[k][c] > bv) { bv = cvS[k][c]; bi = ciS[k][c]; }
        pcv[(size_t)blockIdx.y * LTOK + col] = bv;
        pci[(size_t)blockIdx.y * LTOK + col] = bi;
    }
}

// ---------------- merge 65 argmax partials ----------------
__global__ __launch_bounds__(256) void argmax_combine_kernel(const float* __restrict__ prv,
                                                             const int* __restrict__ pri,
                                                             const float* __restrict__ pcv,
                                                             const int* __restrict__ pci,
                                                             int* __restrict__ idx0,
                                                             float* __restrict__ conf,
                                                             int* __restrict__ idx1)
{
    int id = blockIdx.x * 256 + threadIdx.x;
    if (id >= 2 * LTOK) return;
    if (id < LTOK) {
        float best = -1e30f; int bi = 0;
        for (int i = 0; i < 65; ++i) {
            float v = prv[(size_t)i * LTOK + id];
            if (v > best) { best = v; bi = pri[(size_t)i * LTOK + id]; }
        }
        idx0[id] = bi; conf[id] = best;
    } else {
        int colI = id - LTOK;
        float best = -1e30f; int bi = 0;
        for (int i = 0; i < 65; ++i) {
            float v = pcv[(size_t)i * LTOK + colI];
            if (v > best) { best = v; bi = pci[(size_t)i * LTOK + colI]; }
        }
        idx1[colI] = bi;
    }
}

// ---------------- MHA partial v2b: 64-row Q tile, 4x4 score / 4x2 PV register
//     blocking with ALL-NAMED-SCALAR accumulators (no local arrays -> no
//     scratch; r9 spilled 1.8GB/dispatch via alloca'd locals). ----------------
__global__ __launch_bounds__(256, 3) void mha_partial2_kernel(const float* __restrict__ qkvA,
                                                              const float* __restrict__ qkvB,
                                                              int cross,
                                                              float* __restrict__ part)
{
    __shared__ float Qs[QBLK][36];
    __shared__ float Ks[64][36];
    __shared__ float Vt[32][68];
    __shared__ float Ps[QBLK][68];
    int tid = threadIdx.x;
    int qb = blockIdx.x, ns = blockIdx.z;
    int img = blockIdx.y >> 2, h = blockIdx.y & 3;
    const float* qsrc  = img ? qkvB : qkvA;
    const float* kvsrc = cross ? (img ? qkvA : qkvB) : qsrc;
    int c4 = tid & 15;          // col-thread / d-col base
    int rg = tid >> 4;          // row-group 0..15 -> rows rg*4..rg*4+3
    const int r0 = rg * 4;
    const float sc = 0.17677669529663687f; // 1/sqrt(32)

    // ---- stage Q (64x32), rows clamped at 2079 (outputs for clamped rows unread) ----
    {
        int r = tid >> 2, d8 = (tid & 3) << 3;
        int qr = qb * QBLK + r; qr = qr < LTOK ? qr : (LTOK - 1);
        const float* src = qsrc + (size_t)qr * 384 + h * 32 + d8;
        *(float4*)(&Qs[r][d8])     = *(const float4*)(src);
        *(float4*)(&Qs[r][d8 + 4]) = *(const float4*)(src + 4);
    }
    float a00=0.f,a01=0.f,a10=0.f,a11=0.f,a20=0.f,a21=0.f,a30=0.f,a31=0.f;
    float l0=0.f,l1=0.f,l2=0.f,l3=0.f;
    __syncthreads();

    const int koff = 128 + h * 32, voff = 256 + h * 32;
    for (int t = ns; t < 33; t += NSPLIT2) {
        int j0 = t * 64;
        // ---- stage K (64x32) and V transposed (32x64) ----
        {
            int r = tid >> 3, d4 = (tid & 7) << 2;
            int j1 = j0 + r, j2 = j0 + r + 32;
            float4 k1 = *(const float4*)(kvsrc + (size_t)j1 * 384 + koff + d4);
            float4 v1 = *(const float4*)(kvsrc + (size_t)j1 * 384 + voff + d4);
            float4 k2 = make_float4(0.f, 0.f, 0.f, 0.f);
            float4 v2 = make_float4(0.f, 0.f, 0.f, 0.f);
            if (j2 < LTOK) {
                k2 = *(const float4*)(kvsrc + (size_t)j2 * 384 + koff + d4);
                v2 = *(const float4*)(kvsrc + (size_t)j2 * 384 + voff + d4);
            }
            *(float4*)(&Ks[r][d4])      = k1;
            *(float4*)(&Ks[r + 32][d4]) = k2;
            Vt[d4 + 0][r] = v1.x; Vt[d4 + 1][r] = v1.y; Vt[d4 + 2][r] = v1.z; Vt[d4 + 3][r] = v1.w;
            Vt[d4 + 0][r + 32] = v2.x; Vt[d4 + 1][r + 32] = v2.y; Vt[d4 + 2][r + 32] = v2.z; Vt[d4 + 3][r + 32] = v2.w;
        }
        __syncthreads();
        // ---- score 4x4 (named scalars): rows r0+jj, cols j0 + {0,16,32,48} + c4 ----
        float s00=0.f,s01=0.f,s02=0.f,s03=0.f;
        float s10=0.f,s11=0.f,s12=0.f,s13=0.f;
        float s20=0.f,s21=0.f,s22=0.f,s23=0.f;
        float s30=0.f,s31=0.f,s32=0.f,s33=0.f;
        #pragma unroll
        for (int d4 = 0; d4 < 8; ++d4) {
            const int db = d4 << 2;
            float4 k0 = *(const float4*)(&Ks[c4][db]);
            float4 k1 = *(const float4*)(&Ks[c4 + 16][db]);
            float4 k2 = *(const float4*)(&Ks[c4 + 32][db]);
            float4 k3 = *(const float4*)(&Ks[c4 + 48][db]);
            float4 q0 = *(const float4*)(&Qs[r0 + 0][db]);
            float4 q1 = *(const float4*)(&Qs[r0 + 1][db]);
            float4 q2 = *(const float4*)(&Qs[r0 + 2][db]);
            float4 q3 = *(const float4*)(&Qs[r0 + 3][db]);
            s00 += DOT4(q0,k0); s01 += DOT4(q0,k1); s02 += DOT4(q0,k2); s03 += DOT4(q0,k3);
            s10 += DOT4(q1,k0); s11 += DOT4(q1,k1); s12 += DOT4(q1,k2); s13 += DOT4(q1,k3);
            s20 += DOT4(q2,k0); s21 += DOT4(q2,k1); s22 += DOT4(q2,k2); s23 += DOT4(q2,k3);
            s30 += DOT4(q3,k0); s31 += DOT4(q3,k1); s32 += DOT4(q3,k2); s33 += DOT4(q3,k3);
        }
        // ---- exp + Ps store + row-sum (named scalars, no address-taken locals) ----
        bool ok0 = (j0 + c4) < LTOK;
        bool ok1 = (j0 + 16 + c4) < LTOK;
        bool ok2 = (j0 + 32 + c4) < LTOK;
        bool ok3 = (j0 + 48 + c4) < LTOK;
        {
            float p0 = ok0 ? __expf(s00 * sc) : 0.f;
            float p1 = ok1 ? __expf(s01 * sc) : 0.f;
            float p2 = ok2 ? __expf(s02 * sc) : 0.f;
            float p3 = ok3 ? __expf(s03 * sc) : 0.f;
            l0 += p0 + p1 + p2 + p3;
            Ps[r0 + 0][c4] = p0; Ps[r0 + 0][c4 + 16] = p1; Ps[r0 + 0][c4 + 32] = p2; Ps[r0 + 0][c4 + 48] = p3;
        }
        {
            float p0 = ok0 ? __expf(s10 * sc) : 0.f;
            float p1 = ok1 ? __expf(s11 * sc) : 0.f;
            float p2 = ok2 ? __expf(s12 * sc) : 0.f;
            float p3 = ok3 ? __expf(s13 * sc) : 0.f;
            l1 += p0 + p1 + p2 + p3;
            Ps[r0 + 1][c4] = p0; Ps[r0 + 1][c4 + 16] = p1; Ps[r0 + 1][c4 + 32] = p2; Ps[r0 + 1][c4 + 48] = p3;
        }
        {
            float p0 = ok0 ? __expf(s20 * sc) : 0.f;
            float p1 = ok1 ? __expf(s21 * sc) : 0.f;
            float p2 = ok2 ? __expf(s22 * sc) : 0.f;
            float p3 = ok3 ? __expf(s23 * sc) : 0.f;
            l2 += p0 + p1 + p2 + p3;
            Ps[r0 + 2][c4] = p0; Ps[r0 + 2][c4 + 16] = p1; Ps[r0 + 2][c4 + 32] = p2; Ps[r0 + 2][c4 + 48] = p3;
        }
        {
            float p0 = ok0 ? __expf(s30 * sc) : 0.f;
            float p1 = ok1 ? __expf(s31 * sc) : 0.f;
            float p2 = ok2 ? __expf(s32 * sc) : 0.f;
            float p3 = ok3 ? __expf(s33 * sc) : 0.f;
            l3 += p0 + p1 + p2 + p3;
            Ps[r0 + 3][c4] = p0; Ps[r0 + 3][c4 + 16] = p1; Ps[r0 + 3][c4 + 32] = p2; Ps[r0 + 3][c4 + 48] = p3;
        }
        __syncthreads();
        // ---- PV 4x2 (named scalars): acc[jj][cc] += sum_j Ps[r0+jj][j] * Vt[c4+cc*16][j] ----
        #pragma unroll
        for (int j4 = 0; j4 < 16; ++j4) {
            const int jb = j4 << 2;
            float4 v0 = *(const float4*)(&Vt[c4][jb]);
            float4 v1 = *(const float4*)(&Vt[c4 + 16][jb]);
            float4 pq0 = *(const float4*)(&Ps[r0 + 0][jb]);
            float4 pq1 = *(const float4*)(&Ps[r0 + 1][jb]);
            float4 pq2 = *(const float4*)(&Ps[r0 + 2][jb]);
            float4 pq3 = *(const float4*)(&Ps[r0 + 3][jb]);
            a00 += DOT4(pq0,v0); a01 += DOT4(pq0,v1);
            a10 += DOT4(pq1,v0); a11 += DOT4(pq1,v1);
            a20 += DOT4(pq2,v0); a21 += DOT4(pq2,v1);
            a30 += DOT4(pq3,v0); a31 += DOT4(pq3,v1);
        }
        __syncthreads();
    }
    // ---- store partial: 64x32 acc + 64 l ----
    float* pb = part + (size_t)((((size_t)img * NQB + qb) * NH + h) * NSPLIT2 + ns) * PSTRIDE2;
    pb[(r0 + 0) * 32 + c4]      = a00;
    pb[(r0 + 0) * 32 + c4 + 16] = a01;
    pb[(r0 + 1) * 32 + c4]      = a10;
    pb[(r0 + 1) * 32 + c4 + 16] = a11;
    pb[(r0 + 2) * 32 + c4]      = a20;
    pb[(r0 + 2) * 32 + c4 + 16] = a21;
    pb[(r0 + 3) * 32 + c4]      = a30;
    pb[(r0 + 3) * 32 + c4 + 16] = a31;
    #pragma unroll
    for (int mm = 8; mm >= 1; mm >>= 1) {
        l0 += __shfl_xor(l0, mm, 16);
        l1 += __shfl_xor(l1, mm, 16);
        l2 += __shfl_xor(l2, mm, 16);
        l3 += __shfl_xor(l3, mm, 16);
    }
    if (c4 == 0) {
        pb[2048 + r0 + 0] = l0;
        pb[2048 + r0 + 1] = l1;
        pb[2048 + r0 + 2] = l2;
        pb[2048 + r0 + 3] = l3;
    }
}

// ---------------- MHA combine v2: grid (33, 8) ----------------
__global__ __launch_bounds__(256) void mha_combine2_kernel(const float* __restrict__ part,
                                                           float* __restrict__ out0,
                                                           float* __restrict__ out1)
{
    int tid = threadIdx.x;
    int qb = blockIdx.x;
    int img = blockIdx.y >> 2, h = blockIdx.y & 3;
    float* out = img ? out1 : out0;
    int c = tid & 31, rg8 = tid >> 5;      // 8 groups x 8 rows
    const float* pb = part + (size_t)(((size_t)img * NQB + qb) * NH + h) * NSPLIT2 * PSTRIDE2;
    #pragma unroll
    for (int jj = 0; jj < 8; ++jj) {
        int row = rg8 * 8 + jj;
        int qrow = qb * QBLK + row;
        if (qrow >= LTOK) continue;
        float num = 0.f, den = 0.f;
        #pragma unroll
        for (int ns = 0; ns < NSPLIT2; ++ns) {
            num += pb[ns * PSTRIDE2 + row * 32 + c];
            den += pb[ns * PSTRIDE2 + 2048 + row];
        }
        out[(size_t)qrow * DIM + h * 32 + c] = num / den;
    }
}

// ---------------- residual add + LayerNorm (in place), batched ----------------
__global__ __launch_bounds__(256) void addln_b_kernel(float* __restrict__ f0,
                                                      float* __restrict__ f1,
                                                      const float* __restrict__ t0,
                                                      const float* __restrict__ t1,
                                                      const float* __restrict__ g,
                                                      const float* __restrict__ b)
{
    float* f = blockIdx.y ? f1 : f0;
    const float* t = blockIdx.y ? t1 : t0;
    int row = blockIdx.x * 4 + (threadIdx.x >> 6);
    int lane = threadIdx.x & 63;
    size_t base = (size_t)row * DIM;
    float x0 = f[base + lane] + t[base + lane];
    float x1 = f[base + lane + 64] + t[base + lane + 64];
    float s = x0 + x1;
    #pragma unroll
    for (int mm = 32; mm >= 1; mm >>= 1) s += __shfl_xor(s, mm, 64);
    float mean = s * (1.f / 128.f);
    float d0 = x0 - mean, d1 = x1 - mean;
    float v = d0 * d0 + d1 * d1;
    #pragma unroll
    for (int mm = 32; mm >= 1; mm >>= 1) v += __shfl_xor(v, mm, 64);
    float rstd = rsqrtf(v * (1.f / 128.f) + 1e-5f);
    f[base + lane]      = d0 * rstd * g[lane] + b[lane];
    f[base + lane + 64] = d1 * rstd * g[lane + 64] + b[lane + 64];
}

// ---------------- L2-normalize rows, batched ----------------
__global__ __launch_bounds__(256) void normrows_b_kernel(const float* __restrict__ i0,
                                                         const float* __restrict__ i1,
                                                         float* __restrict__ o0,
                                                         float* __restrict__ o1)
{
    const float* f = blockIdx.y ? i1 : i0;
    float* o = blockIdx.y ? o1 : o0;
    int row = blockIdx.x * 4 + (threadIdx.x >> 6);
    int lane = threadIdx.x & 63;
    size_t base = (size_t)row * DIM;
    float x0 = f[base + lane], x1 = f[base + lane + 64];
    float v = x0 * x0 + x1 * x1;
    #pragma unroll
    for (int mm = 32; mm >= 1; mm >>= 1) v += __shfl_xor(v, mm, 64);
    float inv = 1.f / fmaxf(sqrtf(v), 1e-12f);
    o[base + lane] = x0 * inv;
    o[base + lane + 64] = x1 * inv;
}

// ---------------- match outputs: valid, conf, pt0 ----------------
__global__ __launch_bounds__(256) void match_kernel(const int* __restrict__ idx0,
                                                    const int* __restrict__ idx1,
                                                    const float* __restrict__ conf,
                                                    float* __restrict__ out_valid,
                                                    float* __restrict__ out_conf,
                                                    float* __restrict__ out_pt0)
{
    int i = blockIdx.x * 256 + threadIdx.x;
    if (i >= LTOK) return;
    int j = idx0[i];
    bool valid = (idx1[j] == i) && (conf[i] > 0.2f);
    out_valid[i] = valid ? 1.f : 0.f;
    out_conf[i] = conf[i];
    out_pt0[2 * i]     = (float)(i % W0C) * 8.f + 4.f;
    out_pt0[2 * i + 1] = (float)(i / W0C) * 8.f + 4.f;
}

// ---------------- fine projection, batched ----------------
__global__ __launch_bounds__(256) void fine_proj_b_kernel(const float* __restrict__ fin0,
                                                          const float* __restrict__ fin1,
                                                          const float* __restrict__ w,
                                                          const float* __restrict__ b,
                                                          float* __restrict__ fout0,
                                                          float* __restrict__ fout1)
{
    const float* fin = blockIdx.y ? fin1 : fin0;
    float* fout = blockIdx.y ? fout1 : fout0;
    __shared__ float ws_[32][32];
    __shared__ float bs[32];
    int t = threadIdx.x;
    #pragma unroll
    for (int e = 0; e < 4; ++e) { int l = t + e * 256; ws_[l >> 5][l & 31] = w[l]; }
    if (t < 32) bs[t] = b[t];
    __syncthreads();
    int p = blockIdx.x * 256 + t;
    if (p >= NPIX) return;
    float x[32];
    #pragma unroll
    for (int cc = 0; cc < 32; ++cc) x[cc] = fin[(size_t)cc * NPIX + p];
    #pragma unroll
    for (int o = 0; o < 32; ++o) {
        float a = bs[o];
        #pragma unroll
        for (int cc = 0; cc < 32; ++cc) a += ws_[o][cc] * x[cc];
        fout[(size_t)o * NPIX + p] = a;
    }
}

// ---------------- fine match ----------------
__global__ __launch_bounds__(64) void fine_match_kernel(const int* __restrict__ idx0,
                                                        const float* __restrict__ f0p,
                                                        const float* __restrict__ f1p,
                                                        float* __restrict__ out_pt1)
{
    int i = blockIdx.x;
    int l = threadIdx.x;
    int j = idx0[i];
    int m0x = i % W0C, m0y = i / W0C;
    int m1x = j % W0C, m1y = j / W0C;
    int c0x = m0x * 4, c0y = m0y * 4, c1x = m1x * 4, c1y = m1y * 4;
    bool inb = (c0x - 2 >= 0) && (c0x + 2 < WFI) && (c0y - 2 >= 0) && (c0y + 2 < HFI)
            && (c1x - 2 >= 0) && (c1x + 2 < WFI) && (c1y - 2 >= 0) && (c1y + 2 < HFI);
    int cy0 = min(max(c0y, 2), HFI - 3), cx0 = min(max(c0x, 2), WFI - 3);
    int cy1 = min(max(c1y, 2), HFI - 3), cx1 = min(max(c1x, 2), WFI - 3);
    int dy = l / 5 - 2, dx = l % 5 - 2;
    float corr = -1e30f;
    if (l < 25) {
        float a = 0.f;
        int p0 = cy0 * WFI + cx0;
        int p1 = (cy1 + dy) * WFI + (cx1 + dx);
        #pragma unroll
        for (int cc = 0; cc < 32; ++cc)
            a += f0p[(size_t)cc * NPIX + p0] * f1p[(size_t)cc * NPIX + p1];
        corr = a;
    }
    float mx = corr;
    #pragma unroll
    for (int mm = 32; mm >= 1; mm >>= 1) mx = fmaxf(mx, __shfl_xor(mx, mm, 64));
    float p = (l < 25) ? expf(corr - mx) : 0.f;
    float s = p, sx = p * (float)dx, sy = p * (float)dy;
    #pragma unroll
    for (int mm = 32; mm >= 1; mm >>= 1) {
        s  += __shfl_xor(s, mm, 64);
        sx += __shfl_xor(sx, mm, 64);
        sy += __shfl_xor(sy, mm, 64);
    }
    if (l == 0) {
        float offx = sx / s, offy = sy / s;
        float px = (float)m1x * 8.f + 4.f;
        float py = (float)m1y * 8.f + 4.f;
        if (inb) { px += offx * 2.f; py += offy * 2.f; }
        out_pt1[2 * i]     = px;
        out_pt1[2 * i + 1] = py;
    }
}

// ---------------- host launch ----------------
extern "C" void kernel_launch(void* const* d_in, const int* in_sizes, int n_in,
                              void* d_out, int out_size, void* d_ws, size_t ws_size,
                              hipStream_t stream) {
    (void)in_sizes; (void)n_in; (void)out_size; (void)ws_size;
    const float* coarse0 = (const float*)d_in[0];
    const float* coarse1 = (const float*)d_in[1];
    const float* fine0   = (const float*)d_in[2];
    const float* fine1   = (const float*)d_in[3];
    const float* sa_in_w  = (const float*)d_in[4];
    const float* sa_in_b  = (const float*)d_in[5];
    const float* sa_out_w = (const float*)d_in[6];
    const float* sa_out_b = (const float*)d_in[7];
    const float* ca_in_w  = (const float*)d_in[8];
    const float* ca_in_b  = (const float*)d_in[9];
    const float* ca_out_w = (const float*)d_in[10];
    const float* ca_out_b = (const float*)d_in[11];
    const float* sn_g = (const float*)d_in[12];
    const float* sn_b = (const float*)d_in[13];
    const float* cn_g = (const float*)d_in[14];
    const float* cn_b = (const float*)d_in[15];
    const float* ffn_w1 = (const float*)d_in[16];
    const float* ffn_b1 = (const float*)d_in[17];
    const float* ffn_w2 = (const float*)d_in[18];
    const float* ffn_b2 = (const float*)d_in[19];
    const float* fn_g = (const float*)d_in[20];
    const float* fn_b = (const float*)d_in[21];
    const float* proj_w = (const float*)d_in[22];
    const float* proj_b = (const float*)d_in[23];

    float* w = (float*)d_ws;
    float* f0   = w; w += (size_t)LTOK * DIM;
    float* f1   = w; w += (size_t)LTOK * DIM;
    float* qkv0 = w; w += (size_t)LTOK * 384;
    float* qkv1 = w; w += (size_t)LTOK * 384;
    float* att0 = w; w += (size_t)LTOK * DIM;
    float* att1 = w; w += (size_t)LTOK * DIM;
    float* tmp0 = w; w += (size_t)LTOK * DIM;
    float* tmp1 = w; w += (size_t)LTOK * DIM;
    float* f0n  = w; w += (size_t)LTOK * DIM;
    float* f1n  = w; w += (size_t)LTOK * DIM;
    // R1: time-shared — part (MHA) | hid0/hid1 (FFN) | f0p/f1p (fine)
    float* R1   = w; w += (size_t)2745600;
    float* rowmax = w; w += LTOK;
    float* rsinv  = w; w += LTOK;
    float* colmax = w; w += LTOK;
    float* csinv  = w; w += LTOK;
    float* conf   = w; w += LTOK;
    int* idx0 = (int*)w; w += LTOK;
    int* idx1 = (int*)w; w += LTOK;

    float* part = R1;   // 2*33*4*3*2112 = 1,672,704 floats
    float* hid0 = R1;
    float* hid1 = R1 + (size_t)LTOK * 256;
    float* f0p  = R1;
    float* f1p  = R1 + (size_t)CFCH * NPIX;

    // matching-tail partials alias the (dead after transformer loop) qkv buffers
    float2* prs = (float2*)qkv0;
    float2* pcs = (float2*)(qkv0 + 2 * 65 * LTOK);
    float*  prv = qkv1;
    int*    pri = (int*)(qkv1 + 65 * LTOK);
    float*  pcv = qkv1 + 2 * 65 * LTOK;
    int*    pci = (int*)(qkv1 + 3 * 65 * LTOK);

    float* Pout = (float*)d_out;
    float* out_valid = Pout + (size_t)LTOK * LTOK;
    float* out_conf  = out_valid + LTOK;
    float* out_pt0   = out_conf + LTOK;
    float* out_pt1   = out_pt0 + 2 * LTOK;

    dim3 b256(256);
    dim3 gMHA(NQB, 8, NSPLIT2);
    dim3 gCMB(NQB, 8);
    dim3 gLN(520, 2);
    transpose_b_kernel<<<dim3(65, 4, 2), b256, 0, stream>>>(coarse0, coarse1, f0, f1);

    for (int i = 0; i < 2; ++i) {
        const float* saw = sa_in_w + (size_t)i * 384 * 128;
        const float* sab = sa_in_b + (size_t)i * 384;
        const float* sow = sa_out_w + (size_t)i * 128 * 128;
        const float* sob = sa_out_b + (size_t)i * 128;
        const float* caw = ca_in_w + (size_t)i * 384 * 128;
        const float* cab = ca_in_b + (size_t)i * 384;
        const float* cow = ca_out_w + (size_t)i * 128 * 128;
        const float* cob = ca_out_b + (size_t)i * 128;
        const float* w1 = ffn_w1 + (size_t)i * 256 * 128;
        const float* b1 = ffn_b1 + (size_t)i * 256;
        const float* w2 = ffn_w2 + (size_t)i * 128 * 256;
        const float* b2 = ffn_b2 + (size_t)i * 128;

        // ---- self attention ----
        gemm_nt_b2_kernel<<<dim3(12, 65, 2), b256, 0, stream>>>(f0, f1, 128, saw, 128, qkv0, qkv1, 384, 128, sab, 0);
        mha_partial2_kernel<<<gMHA, b256, 0, stream>>>(qkv0, qkv1, 0, part);
        mha_combine2_kernel<<<gCMB, b256, 0, stream>>>(part, att0, att1);
        gemm_nt_b2_kernel<<<dim3(4, 65, 2), b256, 0, stream>>>(att0, att1, 128, sow, 128, tmp0, tmp1, 128, 128, sob, 0);
        addln_b_kernel<<<gLN, b256, 0, stream>>>(f0, f1, tmp0, tmp1, sn_g + (size_t)i * 128, sn_b + (size_t)i * 128);

        // ---- cross attention ----
        gemm_nt_b2_kernel<<<dim3(12, 65, 2), b256, 0, stream>>>(f0, f1, 128, caw, 128, qkv0, qkv1, 384, 128, cab, 0);
        mha_partial2_kernel<<<gMHA, b256, 0, stream>>>(qkv0, qkv1, 1, part);
        mha_combine2_kernel<<<gCMB, b256, 0, stream>>>(part, att0, att1);
        gemm_nt_b2_kernel<<<dim3(4, 65, 2), b256, 0, stream>>>(att0, att1, 128, cow, 128, tmp0, tmp1, 128, 128, cob, 0);
        addln_b_kernel<<<gLN, b256, 0, stream>>>(f0, f1, tmp0, tmp1, cn_g + (size_t)i * 128, cn_b + (size_t)i * 128);

        // ---- FFN ----
        gemm_nt_b2_kernel<<<dim3(8, 65, 2), b256, 0, stream>>>(f0, f1, 128, w1, 128, hid0, hid1, 256, 128, b1, 1);
        gemm_nt_b2_kernel<<<dim3(4, 65, 2), b256, 0, stream>>>(hid0, hid1, 256, w2, 256, tmp0, tmp1, 128, 256, b2, 0);
        addln_b_kernel<<<gLN, b256, 0, stream>>>(f0, f1, tmp0, tmp1, fn_g + (size_t)i * 128, fn_b + (size_t)i * 128);
    }

    // ---- matching (2 matrix passes total) ----
    normrows_b_kernel<<<gLN, b256, 0, stream>>>(f0, f1, f0n, f1n);
    gemm_score_kernel<<<dim3(65, 65), b256, 0, stream>>>(f0n, f1n, Pout, prs, pcs);
    stats_combine_kernel<<<17, b256, 0, stream>>>(prs, pcs, rowmax, rsinv, colmax, csinv);
    dualp_argmax_kernel<<<dim3(65, 65), b256, 0, stream>>>(Pout, rowmax, rsinv, colmax, csinv,
                                                           prv, pri, pcv, pci);
    argmax_combine_kernel<<<17, b256, 0, stream>>>(prv, pri, pcv, pci, idx0, conf, idx1);
    match_kernel<<<9, b256, 0, stream>>>(idx0, idx1, conf, out_valid, out_conf, out_pt0);

    // ---- fine refinement ----
    fine_proj_b_kernel<<<dim3(130, 2), b256, 0, stream>>>(fine0, fine1, proj_w, proj_b, f0p, f1p);
    fine_match_kernel<<<LTOK, dim3(64), 0, stream>>>(idx0, f0p, f1p, out_pt1);
}

// Round 11
// 798.973 us; speedup vs baseline: 4.4753x; 1.1595x over previous
//
#include <hip/hip_runtime.h>
#include <math.h>

#define LTOK 2080
#define DIM 128
#define NH 4
#define W0C 52
#define HFI 160
#define WFI 208
#define NPIX (HFI*WFI)   // 33280
#define CFCH 32
#define NSPLIT2 6
#define QBLK 64
#define NQB 33           // ceil(2080/64)
#define PSTRIDE2 2112    // 64*32 acc + 64 l

#define DOT4(q,k) ((q).x*(k).x + (q).y*(k).y + (q).z*(k).z + (q).w*(k).w)

// ---------------- transpose (C,L) -> (L,C), batched over 2 images ----------------
__global__ __launch_bounds__(256) void transpose_b_kernel(const float* __restrict__ in0,
                                                          const float* __restrict__ in1,
                                                          float* __restrict__ out0,
                                                          float* __restrict__ out1)
{
    const float* in = blockIdx.z ? in1 : in0;
    float* out = blockIdx.z ? out1 : out0;
    __shared__ float T[32][33];
    int l0 = blockIdx.x * 32, c0 = blockIdx.y * 32;
    int t = threadIdx.x;
    #pragma unroll
    for (int e = 0; e < 4; ++e) {
        int idx = t + e * 256; int i = idx >> 5, j = idx & 31;
        T[i][j] = in[(size_t)(c0 + i) * LTOK + l0 + j];
    }
    __syncthreads();
    #pragma unroll
    for (int e = 0; e < 4; ++e) {
        int idx = t + e * 256; int j2 = idx >> 5, i2 = idx & 31;
        out[(size_t)(l0 + j2) * DIM + c0 + i2] = T[i2][j2];
    }
}

// ---------------- 64x64-tile batched GEMM: Cz = Az(MxK)*B(NxK)^T + bias ----------------
// 256 thr, 4x4 outputs/thread, k-major LDS, float4 reads: 2 b128 per 16 FMA.
// Accumulation order per output = k ascending (bit-identical to 32-tile version).
__global__ __launch_bounds__(256) void gemm64_nt_b2_kernel(const float* __restrict__ A0,
                                                           const float* __restrict__ A1, int lda,
                                                           const float* __restrict__ B, int ldb,
                                                           float* __restrict__ C0,
                                                           float* __restrict__ C1, int ldc,
                                                           int K,
                                                           const float* __restrict__ bias, int relu,
                                                           int M)
{
    const float* A = blockIdx.z ? A1 : A0;
    float* C = blockIdx.z ? C1 : C0;
    __shared__ float As[32][68];
    __shared__ float Bs[32][68];
    int tid = threadIdx.x;
    int n0 = blockIdx.x * 64, m0 = blockIdx.y * 64;
    int cg = tid & 15, rg = tid >> 4;
    int r0 = rg * 4, c0 = cg * 4;
    int srow = tid & 63;    // staging row 0..63
    int skq  = tid >> 6;    // staging k-octet 0..3
    float4 acc0 = make_float4(0.f,0.f,0.f,0.f);
    float4 acc1 = make_float4(0.f,0.f,0.f,0.f);
    float4 acc2 = make_float4(0.f,0.f,0.f,0.f);
    float4 acc3 = make_float4(0.f,0.f,0.f,0.f);

    for (int k0 = 0; k0 < K; k0 += 32) {
        int ar = m0 + srow; ar = ar < M ? ar : M - 1;   // clamped (garbage rows never stored)
        int br = n0 + srow;                             // N multiple of 64
        const float* ap = A + (size_t)ar * lda + k0 + skq * 8;
        const float* bp = B + (size_t)br * ldb + k0 + skq * 8;
        float4 av0 = *(const float4*)(ap);
        float4 av1 = *(const float4*)(ap + 4);
        float4 bv0 = *(const float4*)(bp);
        float4 bv1 = *(const float4*)(bp + 4);
        int kk = skq * 8;
        As[kk+0][srow] = av0.x; As[kk+1][srow] = av0.y; As[kk+2][srow] = av0.z; As[kk+3][srow] = av0.w;
        As[kk+4][srow] = av1.x; As[kk+5][srow] = av1.y; As[kk+6][srow] = av1.z; As[kk+7][srow] = av1.w;
        Bs[kk+0][srow] = bv0.x; Bs[kk+1][srow] = bv0.y; Bs[kk+2][srow] = bv0.z; Bs[kk+3][srow] = bv0.w;
        Bs[kk+4][srow] = bv1.x; Bs[kk+5][srow] = bv1.y; Bs[kk+6][srow] = bv1.z; Bs[kk+7][srow] = bv1.w;
        __syncthreads();
        #pragma unroll
        for (int k = 0; k < 32; ++k) {
            float4 a = *(const float4*)(&As[k][r0]);
            float4 b = *(const float4*)(&Bs[k][c0]);
            acc0.x += a.x*b.x; acc0.y += a.x*b.y; acc0.z += a.x*b.z; acc0.w += a.x*b.w;
            acc1.x += a.y*b.x; acc1.y += a.y*b.y; acc1.z += a.y*b.z; acc1.w += a.y*b.w;
            acc2.x += a.z*b.x; acc2.y += a.z*b.y; acc2.z += a.z*b.z; acc2.w += a.z*b.w;
            acc3.x += a.w*b.x; acc3.y += a.w*b.y; acc3.z += a.w*b.z; acc3.w += a.w*b.w;
        }
        __syncthreads();
    }
    float4 bv = make_float4(0.f,0.f,0.f,0.f);
    if (bias) bv = *(const float4*)(bias + n0 + c0);
    acc0.x += bv.x; acc0.y += bv.y; acc0.z += bv.z; acc0.w += bv.w;
    acc1.x += bv.x; acc1.y += bv.y; acc1.z += bv.z; acc1.w += bv.w;
    acc2.x += bv.x; acc2.y += bv.y; acc2.z += bv.z; acc2.w += bv.w;
    acc3.x += bv.x; acc3.y += bv.y; acc3.z += bv.z; acc3.w += bv.w;
    if (relu) {
        acc0.x = fmaxf(acc0.x, 0.f); acc0.y = fmaxf(acc0.y, 0.f); acc0.z = fmaxf(acc0.z, 0.f); acc0.w = fmaxf(acc0.w, 0.f);
        acc1.x = fmaxf(acc1.x, 0.f); acc1.y = fmaxf(acc1.y, 0.f); acc1.z = fmaxf(acc1.z, 0.f); acc1.w = fmaxf(acc1.w, 0.f);
        acc2.x = fmaxf(acc2.x, 0.f); acc2.y = fmaxf(acc2.y, 0.f); acc2.z = fmaxf(acc2.z, 0.f); acc2.w = fmaxf(acc2.w, 0.f);
        acc3.x = fmaxf(acc3.x, 0.f); acc3.y = fmaxf(acc3.y, 0.f); acc3.z = fmaxf(acc3.z, 0.f); acc3.w = fmaxf(acc3.w, 0.f);
    }
    int gr = m0 + r0;
    if (gr + 0 < M) *(float4*)(C + (size_t)(gr + 0) * ldc + n0 + c0) = acc0;
    if (gr + 1 < M) *(float4*)(C + (size_t)(gr + 1) * ldc + n0 + c0) = acc1;
    if (gr + 2 < M) *(float4*)(C + (size_t)(gr + 2) * ldc + n0 + c0) = acc2;
    if (gr + 3 < M) *(float4*)(C + (size_t)(gr + 3) * ldc + n0 + c0) = acc3;
}

// ---------------- score GEMM + fused softmax-stat partials ----------------
__global__ __launch_bounds__(256) void gemm_score_kernel(const float* __restrict__ A,
                                                         const float* __restrict__ B,
                                                         float* __restrict__ C,
                                                         float2* __restrict__ prs,
                                                         float2* __restrict__ pcs)
{
    __shared__ float As[32][33];
    __shared__ float Bs[32][33];
    __shared__ float cmS[8][32];
    __shared__ float ceS[8][32];
    int tid = threadIdx.x;
    int n0 = blockIdx.x * 32, m0 = blockIdx.y * 32;
    int c = tid & 31, r8 = tid >> 5;
    float acc[4] = {0.f, 0.f, 0.f, 0.f};
    for (int k0 = 0; k0 < 128; k0 += 32) {
        #pragma unroll
        for (int e = 0; e < 4; ++e) {
            int l = tid + e * 256;
            int i = l >> 5, k = l & 31;
            As[k][i] = A[(size_t)(m0 + i) * 128 + k0 + k];
            Bs[k][i] = B[(size_t)(n0 + i) * 128 + k0 + k];
        }
        __syncthreads();
        #pragma unroll
        for (int k = 0; k < 32; ++k) {
            float bv = Bs[k][c];
            #pragma unroll
            for (int jj = 0; jj < 4; ++jj)
                acc[jj] += As[k][4 * r8 + jj] * bv;
        }
        __syncthreads();
    }
    float v[4];
    #pragma unroll
    for (int jj = 0; jj < 4; ++jj) {
        v[jj] = 10.f * acc[jj];
        C[(size_t)(m0 + 4 * r8 + jj) * LTOK + n0 + c] = v[jj];
    }
    #pragma unroll
    for (int jj = 0; jj < 4; ++jj) {
        float m = v[jj];
        #pragma unroll
        for (int mm = 16; mm >= 1; mm >>= 1) m = fmaxf(m, __shfl_xor(m, mm, 32));
        float e = __expf(v[jj] - m);
        #pragma unroll
        for (int mm = 16; mm >= 1; mm >>= 1) e += __shfl_xor(e, mm, 32);
        if (c == 0) prs[(size_t)blockIdx.x * LTOK + m0 + 4 * r8 + jj] = make_float2(m, e);
    }
    float cmx = fmaxf(fmaxf(v[0], v[1]), fmaxf(v[2], v[3]));
    float cex = __expf(v[0] - cmx) + __expf(v[1] - cmx) + __expf(v[2] - cmx) + __expf(v[3] - cmx);
    cmS[r8][c] = cmx; ceS[r8][c] = cex;
    __syncthreads();
    if (r8 == 0) {
        float M = cmS[0][c], S = ceS[0][c];
        #pragma unroll
        for (int k = 1; k < 8; ++k) {
            float m2 = cmS[k][c], s2 = ceS[k][c];
            if (m2 > M) { S = S * __expf(M - m2) + s2; M = m2; }
            else        { S += s2 * __expf(m2 - M); }
        }
        pcs[(size_t)blockIdx.y * LTOK + n0 + c] = make_float2(M, S);
    }
}

// ---------------- merge 65 stat partials per row/col; store max + 1/sum ----------------
__global__ __launch_bounds__(256) void stats_combine_kernel(const float2* __restrict__ prs,
                                                            const float2* __restrict__ pcs,
                                                            float* __restrict__ rowmax,
                                                            float* __restrict__ rsinv,
                                                            float* __restrict__ colmax,
                                                            float* __restrict__ csinv)
{
    int id = blockIdx.x * 256 + threadIdx.x;
    if (id >= 2 * LTOK) return;
    const float2* p = (id < LTOK) ? (prs + id) : (pcs + (id - LTOK));
    float M = -1e30f;
    for (int i = 0; i < 65; ++i) M = fmaxf(M, p[(size_t)i * LTOK].x);
    float S = 0.f;
    for (int i = 0; i < 65; ++i) {
        float2 f = p[(size_t)i * LTOK];
        S += f.y * __expf(f.x - M);
    }
    if (id < LTOK) { rowmax[id] = M; rsinv[id] = 1.f / S; }
    else           { colmax[id - LTOK] = M; csinv[id - LTOK] = 1.f / S; }
}

// ---------------- P = exp(2S-rm-cm)*rsinv*csinv (in place) + argmax partials ----------------
__global__ __launch_bounds__(256) void dualp_argmax_kernel(float* __restrict__ S,
                                                           const float* __restrict__ rm,
                                                           const float* __restrict__ rsinv,
                                                           const float* __restrict__ cm,
                                                           const float* __restrict__ csinv,
                                                           float* __restrict__ prv,
                                                           int* __restrict__ pri,
                                                           float* __restrict__ pcv,
                                                           int* __restrict__ pci)
{
    __shared__ float cvS[8][32];
    __shared__ int   ciS[8][32];
    int tid = threadIdx.x;
    int n0 = blockIdx.x * 32, m0 = blockIdx.y * 32;
    int c = tid & 31, r8 = tid >> 5;
    int col = n0 + c;
    float cmv = cm[col], csv = csinv[col];
    float p[4];
    #pragma unroll
    for (int jj = 0; jj < 4; ++jj) {
        int row = m0 + 4 * r8 + jj;
        size_t o = (size_t)row * LTOK + col;
        float s = S[o];
        float pv = __expf(2.f * s - rm[row] - cmv) * (rsinv[row] * csv);
        S[o] = pv;
        p[jj] = pv;
    }
    #pragma unroll
    for (int jj = 0; jj < 4; ++jj) {
        float bv = p[jj]; int bi = col;
        #pragma unroll
        for (int mm = 16; mm >= 1; mm >>= 1) {
            float ov = __shfl_xor(bv, mm, 32);
            int   oi = __shfl_xor(bi, mm, 32);
            if (ov > bv || (ov == bv && oi < bi)) { bv = ov; bi = oi; }
        }
        if (c == 0) {
            prv[(size_t)blockIdx.x * LTOK + m0 + 4 * r8 + jj] = bv;
            pri[(size_t)blockIdx.x * LTOK + m0 + 4 * r8 + jj] = bi;
        }
    }
    float bv = p[0]; int bi = m0 + 4 * r8;
    #pragma unroll
    for (int jj = 1; jj < 4; ++jj)
        if (p[jj] > bv) { bv = p[jj]; bi = m0 + 4 * r8 + jj; }
    cvS[r8][c] = bv; ciS[r8][c] = bi;
    __syncthreads();
    if (r8 == 0) {
        #pragma unroll
        for (int k = 1; k < 8; ++k)
            if (cvS[k][c] > bv) { bv = cvS[k][c]; bi = ciS[k][c]; }
        pcv[(size_t)blockIdx.y * LTOK + col] = bv;
        pci[(size_t)blockIdx.y * LTOK + col] = bi;
    }
}

// ---------------- merge 65 argmax partials ----------------
__global__ __launch_bounds__(256) void argmax_combine_kernel(const float* __restrict__ prv,
                                                             const int* __restrict__ pri,
                                                             const float* __restrict__ pcv,
                                                             const int* __restrict__ pci,
                                                             int* __restrict__ idx0,
                                                             float* __restrict__ conf,
                                                             int* __restrict__ idx1)
{
    int id = blockIdx.x * 256 + threadIdx.x;
    if (id >= 2 * LTOK) return;
    if (id < LTOK) {
        float best = -1e30f; int bi = 0;
        for (int i = 0; i < 65; ++i) {
            float v = prv[(size_t)i * LTOK + id];
            if (v > best) { best = v; bi = pri[(size_t)i * LTOK + id]; }
        }
        idx0[id] = bi; conf[id] = best;
    } else {
        int colI = id - LTOK;
        float best = -1e30f; int bi = 0;
        for (int i = 0; i < 65; ++i) {
            float v = pcv[(size_t)i * LTOK + colI];
            if (v > best) { best = v; bi = pci[(size_t)i * LTOK + colI]; }
        }
        idx1[colI] = bi;
    }
}

// ---------------- MHA partial v2b (named scalars; NSPLIT2=6 for tail amortization) ----------------
__global__ __launch_bounds__(256, 3) void mha_partial2_kernel(const float* __restrict__ qkvA,
                                                              const float* __restrict__ qkvB,
                                                              int cross,
                                                              float* __restrict__ part)
{
    __shared__ float Qs[QBLK][36];
    __shared__ float Ks[64][36];
    __shared__ float Vt[32][68];
    __shared__ float Ps[QBLK][68];
    int tid = threadIdx.x;
    int qb = blockIdx.x, ns = blockIdx.z;
    int img = blockIdx.y >> 2, h = blockIdx.y & 3;
    const float* qsrc  = img ? qkvB : qkvA;
    const float* kvsrc = cross ? (img ? qkvA : qkvB) : qsrc;
    int c4 = tid & 15;
    int rg = tid >> 4;
    const int r0 = rg * 4;
    const float sc = 0.17677669529663687f; // 1/sqrt(32)

    {
        int r = tid >> 2, d8 = (tid & 3) << 3;
        int qr = qb * QBLK + r; qr = qr < LTOK ? qr : (LTOK - 1);
        const float* src = qsrc + (size_t)qr * 384 + h * 32 + d8;
        *(float4*)(&Qs[r][d8])     = *(const float4*)(src);
        *(float4*)(&Qs[r][d8 + 4]) = *(const float4*)(src + 4);
    }
    float a00=0.f,a01=0.f,a10=0.f,a11=0.f,a20=0.f,a21=0.f,a30=0.f,a31=0.f;
    float l0=0.f,l1=0.f,l2=0.f,l3=0.f;
    __syncthreads();

    const int koff = 128 + h * 32, voff = 256 + h * 32;
    for (int t = ns; t < 33; t += NSPLIT2) {
        int j0 = t * 64;
        {
            int r = tid >> 3, d4 = (tid & 7) << 2;
            int j1 = j0 + r, j2 = j0 + r + 32;
            float4 k1 = *(const float4*)(kvsrc + (size_t)j1 * 384 + koff + d4);
            float4 v1 = *(const float4*)(kvsrc + (size_t)j1 * 384 + voff + d4);
            float4 k2 = make_float4(0.f, 0.f, 0.f, 0.f);
            float4 v2 = make_float4(0.f, 0.f, 0.f, 0.f);
            if (j2 < LTOK) {
                k2 = *(const float4*)(kvsrc + (size_t)j2 * 384 + koff + d4);
                v2 = *(const float4*)(kvsrc + (size_t)j2 * 384 + voff + d4);
            }
            *(float4*)(&Ks[r][d4])      = k1;
            *(float4*)(&Ks[r + 32][d4]) = k2;
            Vt[d4 + 0][r] = v1.x; Vt[d4 + 1][r] = v1.y; Vt[d4 + 2][r] = v1.z; Vt[d4 + 3][r] = v1.w;
            Vt[d4 + 0][r + 32] = v2.x; Vt[d4 + 1][r + 32] = v2.y; Vt[d4 + 2][r + 32] = v2.z; Vt[d4 + 3][r + 32] = v2.w;
        }
        __syncthreads();
        float s00=0.f,s01=0.f,s02=0.f,s03=0.f;
        float s10=0.f,s11=0.f,s12=0.f,s13=0.f;
        float s20=0.f,s21=0.f,s22=0.f,s23=0.f;
        float s30=0.f,s31=0.f,s32=0.f,s33=0.f;
        #pragma unroll
        for (int d4 = 0; d4 < 8; ++d4) {
            const int db = d4 << 2;
            float4 k0 = *(const float4*)(&Ks[c4][db]);
            float4 k1 = *(const float4*)(&Ks[c4 + 16][db]);
            float4 k2 = *(const float4*)(&Ks[c4 + 32][db]);
            float4 k3 = *(const float4*)(&Ks[c4 + 48][db]);
            float4 q0 = *(const float4*)(&Qs[r0 + 0][db]);
            float4 q1 = *(const float4*)(&Qs[r0 + 1][db]);
            float4 q2 = *(const float4*)(&Qs[r0 + 2][db]);
            float4 q3 = *(const float4*)(&Qs[r0 + 3][db]);
            s00 += DOT4(q0,k0); s01 += DOT4(q0,k1); s02 += DOT4(q0,k2); s03 += DOT4(q0,k3);
            s10 += DOT4(q1,k0); s11 += DOT4(q1,k1); s12 += DOT4(q1,k2); s13 += DOT4(q1,k3);
            s20 += DOT4(q2,k0); s21 += DOT4(q2,k1); s22 += DOT4(q2,k2); s23 += DOT4(q2,k3);
            s30 += DOT4(q3,k0); s31 += DOT4(q3,k1); s32 += DOT4(q3,k2); s33 += DOT4(q3,k3);
        }
        bool ok0 = (j0 + c4) < LTOK;
        bool ok1 = (j0 + 16 + c4) < LTOK;
        bool ok2 = (j0 + 32 + c4) < LTOK;
        bool ok3 = (j0 + 48 + c4) < LTOK;
        {
            float p0 = ok0 ? __expf(s00 * sc) : 0.f;
            float p1 = ok1 ? __expf(s01 * sc) : 0.f;
            float p2 = ok2 ? __expf(s02 * sc) : 0.f;
            float p3 = ok3 ? __expf(s03 * sc) : 0.f;
            l0 += p0 + p1 + p2 + p3;
            Ps[r0 + 0][c4] = p0; Ps[r0 + 0][c4 + 16] = p1; Ps[r0 + 0][c4 + 32] = p2; Ps[r0 + 0][c4 + 48] = p3;
        }
        {
            float p0 = ok0 ? __expf(s10 * sc) : 0.f;
            float p1 = ok1 ? __expf(s11 * sc) : 0.f;
            float p2 = ok2 ? __expf(s12 * sc) : 0.f;
            float p3 = ok3 ? __expf(s13 * sc) : 0.f;
            l1 += p0 + p1 + p2 + p3;
            Ps[r0 + 1][c4] = p0; Ps[r0 + 1][c4 + 16] = p1; Ps[r0 + 1][c4 + 32] = p2; Ps[r0 + 1][c4 + 48] = p3;
        }
        {
            float p0 = ok0 ? __expf(s20 * sc) : 0.f;
            float p1 = ok1 ? __expf(s21 * sc) : 0.f;
            float p2 = ok2 ? __expf(s22 * sc) : 0.f;
            float p3 = ok3 ? __expf(s23 * sc) : 0.f;
            l2 += p0 + p1 + p2 + p3;
            Ps[r0 + 2][c4] = p0; Ps[r0 + 2][c4 + 16] = p1; Ps[r0 + 2][c4 + 32] = p2; Ps[r0 + 2][c4 + 48] = p3;
        }
        {
            float p0 = ok0 ? __expf(s30 * sc) : 0.f;
            float p1 = ok1 ? __expf(s31 * sc) : 0.f;
            float p2 = ok2 ? __expf(s32 * sc) : 0.f;
            float p3 = ok3 ? __expf(s33 * sc) : 0.f;
            l3 += p0 + p1 + p2 + p3;
            Ps[r0 + 3][c4] = p0; Ps[r0 + 3][c4 + 16] = p1; Ps[r0 + 3][c4 + 32] = p2; Ps[r0 + 3][c4 + 48] = p3;
        }
        __syncthreads();
        #pragma unroll
        for (int j4 = 0; j4 < 16; ++j4) {
            const int jb = j4 << 2;
            float4 v0 = *(const float4*)(&Vt[c4][jb]);
            float4 v1 = *(const float4*)(&Vt[c4 + 16][jb]);
            float4 pq0 = *(const float4*)(&Ps[r0 + 0][jb]);
            float4 pq1 = *(const float4*)(&Ps[r0 + 1][jb]);
            float4 pq2 = *(const float4*)(&Ps[r0 + 2][jb]);
            float4 pq3 = *(const float4*)(&Ps[r0 + 3][jb]);
            a00 += DOT4(pq0,v0); a01 += DOT4(pq0,v1);
            a10 += DOT4(pq1,v0); a11 += DOT4(pq1,v1);
            a20 += DOT4(pq2,v0); a21 += DOT4(pq2,v1);
            a30 += DOT4(pq3,v0); a31 += DOT4(pq3,v1);
        }
        __syncthreads();
    }
    float* pb = part + (size_t)((((size_t)img * NQB + qb) * NH + h) * NSPLIT2 + ns) * PSTRIDE2;
    pb[(r0 + 0) * 32 + c4]      = a00;
    pb[(r0 + 0) * 32 + c4 + 16] = a01;
    pb[(r0 + 1) * 32 + c4]      = a10;
    pb[(r0 + 1) * 32 + c4 + 16] = a11;
    pb[(r0 + 2) * 32 + c4]      = a20;
    pb[(r0 + 2) * 32 + c4 + 16] = a21;
    pb[(r0 + 3) * 32 + c4]      = a30;
    pb[(r0 + 3) * 32 + c4 + 16] = a31;
    #pragma unroll
    for (int mm = 8; mm >= 1; mm >>= 1) {
        l0 += __shfl_xor(l0, mm, 16);
        l1 += __shfl_xor(l1, mm, 16);
        l2 += __shfl_xor(l2, mm, 16);
        l3 += __shfl_xor(l3, mm, 16);
    }
    if (c4 == 0) {
        pb[2048 + r0 + 0] = l0;
        pb[2048 + r0 + 1] = l1;
        pb[2048 + r0 + 2] = l2;
        pb[2048 + r0 + 3] = l3;
    }
}

// ---------------- MHA combine v2: grid (33, 8) ----------------
__global__ __launch_bounds__(256) void mha_combine2_kernel(const float* __restrict__ part,
                                                           float* __restrict__ out0,
                                                           float* __restrict__ out1)
{
    int tid = threadIdx.x;
    int qb = blockIdx.x;
    int img = blockIdx.y >> 2, h = blockIdx.y & 3;
    float* out = img ? out1 : out0;
    int c = tid & 31, rg8 = tid >> 5;
    const float* pb = part + (size_t)(((size_t)img * NQB + qb) * NH + h) * NSPLIT2 * PSTRIDE2;
    #pragma unroll
    for (int jj = 0; jj < 8; ++jj) {
        int row = rg8 * 8 + jj;
        int qrow = qb * QBLK + row;
        if (qrow >= LTOK) continue;
        float num = 0.f, den = 0.f;
        #pragma unroll
        for (int ns = 0; ns < NSPLIT2; ++ns) {
            num += pb[ns * PSTRIDE2 + row * 32 + c];
            den += pb[ns * PSTRIDE2 + 2048 + row];
        }
        out[(size_t)qrow * DIM + h * 32 + c] = num / den;
    }
}

// ---------------- residual add + LayerNorm (in place), batched ----------------
__global__ __launch_bounds__(256) void addln_b_kernel(float* __restrict__ f0,
                                                      float* __restrict__ f1,
                                                      const float* __restrict__ t0,
                                                      const float* __restrict__ t1,
                                                      const float* __restrict__ g,
                                                      const float* __restrict__ b)
{
    float* f = blockIdx.y ? f1 : f0;
    const float* t = blockIdx.y ? t1 : t0;
    int row = blockIdx.x * 4 + (threadIdx.x >> 6);
    int lane = threadIdx.x & 63;
    size_t base = (size_t)row * DIM;
    float x0 = f[base + lane] + t[base + lane];
    float x1 = f[base + lane + 64] + t[base + lane + 64];
    float s = x0 + x1;
    #pragma unroll
    for (int mm = 32; mm >= 1; mm >>= 1) s += __shfl_xor(s, mm, 64);
    float mean = s * (1.f / 128.f);
    float d0 = x0 - mean, d1 = x1 - mean;
    float v = d0 * d0 + d1 * d1;
    #pragma unroll
    for (int mm = 32; mm >= 1; mm >>= 1) v += __shfl_xor(v, mm, 64);
    float rstd = rsqrtf(v * (1.f / 128.f) + 1e-5f);
    f[base + lane]      = d0 * rstd * g[lane] + b[lane];
    f[base + lane + 64] = d1 * rstd * g[lane + 64] + b[lane + 64];
}

// ---------------- L2-normalize rows, batched ----------------
__global__ __launch_bounds__(256) void normrows_b_kernel(const float* __restrict__ i0,
                                                         const float* __restrict__ i1,
                                                         float* __restrict__ o0,
                                                         float* __restrict__ o1)
{
    const float* f = blockIdx.y ? i1 : i0;
    float* o = blockIdx.y ? o1 : o0;
    int row = blockIdx.x * 4 + (threadIdx.x >> 6);
    int lane = threadIdx.x & 63;
    size_t base = (size_t)row * DIM;
    float x0 = f[base + lane], x1 = f[base + lane + 64];
    float v = x0 * x0 + x1 * x1;
    #pragma unroll
    for (int mm = 32; mm >= 1; mm >>= 1) v += __shfl_xor(v, mm, 64);
    float inv = 1.f / fmaxf(sqrtf(v), 1e-12f);
    o[base + lane] = x0 * inv;
    o[base + lane + 64] = x1 * inv;
}

// ---------------- match outputs: valid, conf, pt0 ----------------
__global__ __launch_bounds__(256) void match_kernel(const int* __restrict__ idx0,
                                                    const int* __restrict__ idx1,
                                                    const float* __restrict__ conf,
                                                    float* __restrict__ out_valid,
                                                    float* __restrict__ out_conf,
                                                    float* __restrict__ out_pt0)
{
    int i = blockIdx.x * 256 + threadIdx.x;
    if (i >= LTOK) return;
    int j = idx0[i];
    bool valid = (idx1[j] == i) && (conf[i] > 0.2f);
    out_valid[i] = valid ? 1.f : 0.f;
    out_conf[i] = conf[i];
    out_pt0[2 * i]     = (float)(i % W0C) * 8.f + 4.f;
    out_pt0[2 * i + 1] = (float)(i / W0C) * 8.f + 4.f;
}

// ---------------- fine projection, batched ----------------
__global__ __launch_bounds__(256) void fine_proj_b_kernel(const float* __restrict__ fin0,
                                                          const float* __restrict__ fin1,
                                                          const float* __restrict__ w,
                                                          const float* __restrict__ b,
                                                          float* __restrict__ fout0,
                                                          float* __restrict__ fout1)
{
    const float* fin = blockIdx.y ? fin1 : fin0;
    float* fout = blockIdx.y ? fout1 : fout0;
    __shared__ float ws_[32][32];
    __shared__ float bs[32];
    int t = threadIdx.x;
    #pragma unroll
    for (int e = 0; e < 4; ++e) { int l = t + e * 256; ws_[l >> 5][l & 31] = w[l]; }
    if (t < 32) bs[t] = b[t];
    __syncthreads();
    int p = blockIdx.x * 256 + t;
    if (p >= NPIX) return;
    float x[32];
    #pragma unroll
    for (int cc = 0; cc < 32; ++cc) x[cc] = fin[(size_t)cc * NPIX + p];
    #pragma unroll
    for (int o = 0; o < 32; ++o) {
        float a = bs[o];
        #pragma unroll
        for (int cc = 0; cc < 32; ++cc) a += ws_[o][cc] * x[cc];
        fout[(size_t)o * NPIX + p] = a;
    }
}

// ---------------- fine match ----------------
__global__ __launch_bounds__(64) void fine_match_kernel(const int* __restrict__ idx0,
                                                        const float* __restrict__ f0p,
                                                        const float* __restrict__ f1p,
                                                        float* __restrict__ out_pt1)
{
    int i = blockIdx.x;
    int l = threadIdx.x;
    int j = idx0[i];
    int m0x = i % W0C, m0y = i / W0C;
    int m1x = j % W0C, m1y = j / W0C;
    int c0x = m0x * 4, c0y = m0y * 4, c1x = m1x * 4, c1y = m1y * 4;
    bool inb = (c0x - 2 >= 0) && (c0x + 2 < WFI) && (c0y - 2 >= 0) && (c0y + 2 < HFI)
            && (c1x - 2 >= 0) && (c1x + 2 < WFI) && (c1y - 2 >= 0) && (c1y + 2 < HFI);
    int cy0 = min(max(c0y, 2), HFI - 3), cx0 = min(max(c0x, 2), WFI - 3);
    int cy1 = min(max(c1y, 2), HFI - 3), cx1 = min(max(c1x, 2), WFI - 3);
    int dy = l / 5 - 2, dx = l % 5 - 2;
    float corr = -1e30f;
    if (l < 25) {
        float a = 0.f;
        int p0 = cy0 * WFI + cx0;
        int p1 = (cy1 + dy) * WFI + (cx1 + dx);
        #pragma unroll
        for (int cc = 0; cc < 32; ++cc)
            a += f0p[(size_t)cc * NPIX + p0] * f1p[(size_t)cc * NPIX + p1];
        corr = a;
    }
    float mx = corr;
    #pragma unroll
    for (int mm = 32; mm >= 1; mm >>= 1) mx = fmaxf(mx, __shfl_xor(mx, mm, 64));
    float p = (l < 25) ? expf(corr - mx) : 0.f;
    float s = p, sx = p * (float)dx, sy = p * (float)dy;
    #pragma unroll
    for (int mm = 32; mm >= 1; mm >>= 1) {
        s  += __shfl_xor(s, mm, 64);
        sx += __shfl_xor(sx, mm, 64);
        sy += __shfl_xor(sy, mm, 64);
    }
    if (l == 0) {
        float offx = sx / s, offy = sy / s;
        float px = (float)m1x * 8.f + 4.f;
        float py = (float)m1y * 8.f + 4.f;
        if (inb) { px += offx * 2.f; py += offy * 2.f; }
        out_pt1[2 * i]     = px;
        out_pt1[2 * i + 1] = py;
    }
}

// ---------------- host launch ----------------
extern "C" void kernel_launch(void* const* d_in, const int* in_sizes, int n_in,
                              void* d_out, int out_size, void* d_ws, size_t ws_size,
                              hipStream_t stream) {
    (void)in_sizes; (void)n_in; (void)out_size; (void)ws_size;
    const float* coarse0 = (const float*)d_in[0];
    const float* coarse1 = (const float*)d_in[1];
    const float* fine0   = (const float*)d_in[2];
    const float* fine1   = (const float*)d_in[3];
    const float* sa_in_w  = (const float*)d_in[4];
    const float* sa_in_b  = (const float*)d_in[5];
    const float* sa_out_w = (const float*)d_in[6];
    const float* sa_out_b = (const float*)d_in[7];
    const float* ca_in_w  = (const float*)d_in[8];
    const float* ca_in_b  = (const float*)d_in[9];
    const float* ca_out_w = (const float*)d_in[10];
    const float* ca_out_b = (const float*)d_in[11];
    const float* sn_g = (const float*)d_in[12];
    const float* sn_b = (const float*)d_in[13];
    const float* cn_g = (const float*)d_in[14];
    const float* cn_b = (const float*)d_in[15];
    const float* ffn_w1 = (const float*)d_in[16];
    const float* ffn_b1 = (const float*)d_in[17];
    const float* ffn_w2 = (const float*)d_in[18];
    const float* ffn_b2 = (const float*)d_in[19];
    const float* fn_g = (const float*)d_in[20];
    const float* fn_b = (const float*)d_in[21];
    const float* proj_w = (const float*)d_in[22];
    const float* proj_b = (const float*)d_in[23];

    float* w = (float*)d_ws;
    float* f0   = w; w += (size_t)LTOK * DIM;
    float* f1   = w; w += (size_t)LTOK * DIM;
    float* qkv0 = w; w += (size_t)LTOK * 384;
    float* qkv1 = w; w += (size_t)LTOK * 384;
    float* att0 = w; w += (size_t)LTOK * DIM;
    float* att1 = w; w += (size_t)LTOK * DIM;
    float* tmp0 = w; w += (size_t)LTOK * DIM;
    float* tmp1 = w; w += (size_t)LTOK * DIM;
    float* f0n  = w; w += (size_t)LTOK * DIM;
    float* f1n  = w; w += (size_t)LTOK * DIM;
    // R1: time-shared — part (MHA, 2*33*4*6*2112 = 3,345,408 fl) | hid (FFN) | f0p/f1p (fine)
    float* R1   = w; w += (size_t)3345408;
    float* rowmax = w; w += LTOK;
    float* rsinv  = w; w += LTOK;
    float* colmax = w; w += LTOK;
    float* csinv  = w; w += LTOK;
    float* conf   = w; w += LTOK;
    int* idx0 = (int*)w; w += LTOK;
    int* idx1 = (int*)w; w += LTOK;

    float* part = R1;
    float* hid0 = R1;
    float* hid1 = R1 + (size_t)LTOK * 256;
    float* f0p  = R1;
    float* f1p  = R1 + (size_t)CFCH * NPIX;

    float2* prs = (float2*)qkv0;
    float2* pcs = (float2*)(qkv0 + 2 * 65 * LTOK);
    float*  prv = qkv1;
    int*    pri = (int*)(qkv1 + 65 * LTOK);
    float*  pcv = qkv1 + 2 * 65 * LTOK;
    int*    pci = (int*)(qkv1 + 3 * 65 * LTOK);

    float* Pout = (float*)d_out;
    float* out_valid = Pout + (size_t)LTOK * LTOK;
    float* out_conf  = out_valid + LTOK;
    float* out_pt0   = out_conf + LTOK;
    float* out_pt1   = out_pt0 + 2 * LTOK;

    dim3 b256(256);
    dim3 gMHA(NQB, 8, NSPLIT2);
    dim3 gCMB(NQB, 8);
    dim3 gLN(520, 2);
    transpose_b_kernel<<<dim3(65, 4, 2), b256, 0, stream>>>(coarse0, coarse1, f0, f1);

    for (int i = 0; i < 2; ++i) {
        const float* saw = sa_in_w + (size_t)i * 384 * 128;
        const float* sab = sa_in_b + (size_t)i * 384;
        const float* sow = sa_out_w + (size_t)i * 128 * 128;
        const float* sob = sa_out_b + (size_t)i * 128;
        const float* caw = ca_in_w + (size_t)i * 384 * 128;
        const float* cab = ca_in_b + (size_t)i * 384;
        const float* cow = ca_out_w + (size_t)i * 128 * 128;
        const float* cob = ca_out_b + (size_t)i * 128;
        const float* w1 = ffn_w1 + (size_t)i * 256 * 128;
        const float* b1 = ffn_b1 + (size_t)i * 256;
        const float* w2 = ffn_w2 + (size_t)i * 128 * 256;
        const float* b2 = ffn_b2 + (size_t)i * 128;

        // ---- self attention ----
        gemm64_nt_b2_kernel<<<dim3(6, 33, 2), b256, 0, stream>>>(f0, f1, 128, saw, 128, qkv0, qkv1, 384, 128, sab, 0, LTOK);
        mha_partial2_kernel<<<gMHA, b256, 0, stream>>>(qkv0, qkv1, 0, part);
        mha_combine2_kernel<<<gCMB, b256, 0, stream>>>(part, att0, att1);
        gemm64_nt_b2_kernel<<<dim3(2, 33, 2), b256, 0, stream>>>(att0, att1, 128, sow, 128, tmp0, tmp1, 128, 128, sob, 0, LTOK);
        addln_b_kernel<<<gLN, b256, 0, stream>>>(f0, f1, tmp0, tmp1, sn_g + (size_t)i * 128, sn_b + (size_t)i * 128);

        // ---- cross attention ----
        gemm64_nt_b2_kernel<<<dim3(6, 33, 2), b256, 0, stream>>>(f0, f1, 128, caw, 128, qkv0, qkv1, 384, 128, cab, 0, LTOK);
        mha_partial2_kernel<<<gMHA, b256, 0, stream>>>(qkv0, qkv1, 1, part);
        mha_combine2_kernel<<<gCMB, b256, 0, stream>>>(part, att0, att1);
        gemm64_nt_b2_kernel<<<dim3(2, 33, 2), b256, 0, stream>>>(att0, att1, 128, cow, 128, tmp0, tmp1, 128, 128, cob, 0, LTOK);
        addln_b_kernel<<<gLN, b256, 0, stream>>>(f0, f1, tmp0, tmp1, cn_g + (size_t)i * 128, cn_b + (size_t)i * 128);

        // ---- FFN ----
        gemm64_nt_b2_kernel<<<dim3(4, 33, 2), b256, 0, stream>>>(f0, f1, 128, w1, 128, hid0, hid1, 256, 128, b1, 1, LTOK);
        gemm64_nt_b2_kernel<<<dim3(2, 33, 2), b256, 0, stream>>>(hid0, hid1, 256, w2, 256, tmp0, tmp1, 128, 256, b2, 0, LTOK);
        addln_b_kernel<<<gLN, b256, 0, stream>>>(f0, f1, tmp0, tmp1, fn_g + (size_t)i * 128, fn_b + (size_t)i * 128);
    }

    // ---- matching (2 matrix passes total) ----
    normrows_b_kernel<<<gLN, b256, 0, stream>>>(f0, f1, f0n, f1n);
    gemm_score_kernel<<<dim3(65, 65), b256, 0, stream>>>(f0n, f1n, Pout, prs, pcs);
    stats_combine_kernel<<<17, b256, 0, stream>>>(prs, pcs, rowmax, rsinv, colmax, csinv);
    dualp_argmax_kernel<<<dim3(65, 65), b256, 0, stream>>>(Pout, rowmax, rsinv, colmax, csinv,
                                                           prv, pri, pcv, pci);
    argmax_combine_kernel<<<17, b256, 0, stream>>>(prv, pri, pcv, pci, idx0, conf, idx1);
    match_kernel<<<9, b256, 0, stream>>>(idx0, idx1, conf, out_valid, out_conf, out_pt0);

    // ---- fine refinement ----
    fine_proj_b_kernel<<<dim3(130, 2), b256, 0, stream>>>(fine0, fine1, proj_w, proj_b, f0p, f1p);
    fine_match_kernel<<<LTOK, dim3(64), 0, stream>>>(idx0, f0p, f1p, out_pt1);
}

// Round 12
// 783.596 us; speedup vs baseline: 4.5631x; 1.0196x over previous
//
#include <hip/hip_runtime.h>
#include <math.h>

#define LTOK 2080
#define DIM 128
#define NH 4
#define W0C 52
#define HFI 160
#define WFI 208
#define NPIX (HFI*WFI)   // 33280
#define CFCH 32
#define NSPLIT2 6
#define QBLK 64
#define NQB 33           // ceil(2080/64)
#define PSTRIDE2 2112    // 64*32 acc + 64 l
#define NST 33           // score-tile count (64-wide)

#define DOT4(q,k) ((q).x*(k).x + (q).y*(k).y + (q).z*(k).z + (q).w*(k).w)

// ---------------- transpose (C,L) -> (L,C), batched over 2 images ----------------
__global__ __launch_bounds__(256) void transpose_b_kernel(const float* __restrict__ in0,
                                                          const float* __restrict__ in1,
                                                          float* __restrict__ out0,
                                                          float* __restrict__ out1)
{
    const float* in = blockIdx.z ? in1 : in0;
    float* out = blockIdx.z ? out1 : out0;
    __shared__ float T[32][33];
    int l0 = blockIdx.x * 32, c0 = blockIdx.y * 32;
    int t = threadIdx.x;
    #pragma unroll
    for (int e = 0; e < 4; ++e) {
        int idx = t + e * 256; int i = idx >> 5, j = idx & 31;
        T[i][j] = in[(size_t)(c0 + i) * LTOK + l0 + j];
    }
    __syncthreads();
    #pragma unroll
    for (int e = 0; e < 4; ++e) {
        int idx = t + e * 256; int j2 = idx >> 5, i2 = idx & 31;
        out[(size_t)(l0 + j2) * DIM + c0 + i2] = T[i2][j2];
    }
}

// ---------------- 64x64-tile batched GEMM: Cz = Az(MxK)*B(NxK)^T + bias ----------------
__global__ __launch_bounds__(256) void gemm64_nt_b2_kernel(const float* __restrict__ A0,
                                                           const float* __restrict__ A1, int lda,
                                                           const float* __restrict__ B, int ldb,
                                                           float* __restrict__ C0,
                                                           float* __restrict__ C1, int ldc,
                                                           int K,
                                                           const float* __restrict__ bias, int relu,
                                                           int M)
{
    const float* A = blockIdx.z ? A1 : A0;
    float* C = blockIdx.z ? C1 : C0;
    __shared__ float As[32][68];
    __shared__ float Bs[32][68];
    int tid = threadIdx.x;
    int n0 = blockIdx.x * 64, m0 = blockIdx.y * 64;
    int cg = tid & 15, rg = tid >> 4;
    int r0 = rg * 4, c0 = cg * 4;
    int srow = tid & 63;
    int skq  = tid >> 6;
    float4 acc0 = make_float4(0.f,0.f,0.f,0.f);
    float4 acc1 = make_float4(0.f,0.f,0.f,0.f);
    float4 acc2 = make_float4(0.f,0.f,0.f,0.f);
    float4 acc3 = make_float4(0.f,0.f,0.f,0.f);

    for (int k0 = 0; k0 < K; k0 += 32) {
        int ar = m0 + srow; ar = ar < M ? ar : M - 1;
        int br = n0 + srow;
        const float* ap = A + (size_t)ar * lda + k0 + skq * 8;
        const float* bp = B + (size_t)br * ldb + k0 + skq * 8;
        float4 av0 = *(const float4*)(ap);
        float4 av1 = *(const float4*)(ap + 4);
        float4 bv0 = *(const float4*)(bp);
        float4 bv1 = *(const float4*)(bp + 4);
        int kk = skq * 8;
        As[kk+0][srow] = av0.x; As[kk+1][srow] = av0.y; As[kk+2][srow] = av0.z; As[kk+3][srow] = av0.w;
        As[kk+4][srow] = av1.x; As[kk+5][srow] = av1.y; As[kk+6][srow] = av1.z; As[kk+7][srow] = av1.w;
        Bs[kk+0][srow] = bv0.x; Bs[kk+1][srow] = bv0.y; Bs[kk+2][srow] = bv0.z; Bs[kk+3][srow] = bv0.w;
        Bs[kk+4][srow] = bv1.x; Bs[kk+5][srow] = bv1.y; Bs[kk+6][srow] = bv1.z; Bs[kk+7][srow] = bv1.w;
        __syncthreads();
        #pragma unroll
        for (int k = 0; k < 32; ++k) {
            float4 a = *(const float4*)(&As[k][r0]);
            float4 b = *(const float4*)(&Bs[k][c0]);
            acc0.x += a.x*b.x; acc0.y += a.x*b.y; acc0.z += a.x*b.z; acc0.w += a.x*b.w;
            acc1.x += a.y*b.x; acc1.y += a.y*b.y; acc1.z += a.y*b.z; acc1.w += a.y*b.w;
            acc2.x += a.z*b.x; acc2.y += a.z*b.y; acc2.z += a.z*b.z; acc2.w += a.z*b.w;
            acc3.x += a.w*b.x; acc3.y += a.w*b.y; acc3.z += a.w*b.z; acc3.w += a.w*b.w;
        }
        __syncthreads();
    }
    float4 bv = make_float4(0.f,0.f,0.f,0.f);
    if (bias) bv = *(const float4*)(bias + n0 + c0);
    acc0.x += bv.x; acc0.y += bv.y; acc0.z += bv.z; acc0.w += bv.w;
    acc1.x += bv.x; acc1.y += bv.y; acc1.z += bv.z; acc1.w += bv.w;
    acc2.x += bv.x; acc2.y += bv.y; acc2.z += bv.z; acc2.w += bv.w;
    acc3.x += bv.x; acc3.y += bv.y; acc3.z += bv.z; acc3.w += bv.w;
    if (relu) {
        acc0.x = fmaxf(acc0.x, 0.f); acc0.y = fmaxf(acc0.y, 0.f); acc0.z = fmaxf(acc0.z, 0.f); acc0.w = fmaxf(acc0.w, 0.f);
        acc1.x = fmaxf(acc1.x, 0.f); acc1.y = fmaxf(acc1.y, 0.f); acc1.z = fmaxf(acc1.z, 0.f); acc1.w = fmaxf(acc1.w, 0.f);
        acc2.x = fmaxf(acc2.x, 0.f); acc2.y = fmaxf(acc2.y, 0.f); acc2.z = fmaxf(acc2.z, 0.f); acc2.w = fmaxf(acc2.w, 0.f);
        acc3.x = fmaxf(acc3.x, 0.f); acc3.y = fmaxf(acc3.y, 0.f); acc3.z = fmaxf(acc3.z, 0.f); acc3.w = fmaxf(acc3.w, 0.f);
    }
    int gr = m0 + r0;
    if (gr + 0 < M) *(float4*)(C + (size_t)(gr + 0) * ldc + n0 + c0) = acc0;
    if (gr + 1 < M) *(float4*)(C + (size_t)(gr + 1) * ldc + n0 + c0) = acc1;
    if (gr + 2 < M) *(float4*)(C + (size_t)(gr + 2) * ldc + n0 + c0) = acc2;
    if (gr + 3 < M) *(float4*)(C + (size_t)(gr + 3) * ldc + n0 + c0) = acc3;
}

// ---------------- 64x64-tile score GEMM + fused softmax-stat partials ----------------
// S = 10 * A(2080x128) B(2080x128)^T. grid (33,33).
// prs[bx*LTOK+row] = (max, sum exp(v-max)) over this tile's valid cols.
// pcs[by*LTOK+col] = same over this tile's valid rows.
__global__ __launch_bounds__(256) void gemm_score64_kernel(const float* __restrict__ A,
                                                           const float* __restrict__ B,
                                                           float* __restrict__ C,
                                                           float2* __restrict__ prs,
                                                           float2* __restrict__ pcs)
{
    __shared__ float As[32][68];
    __shared__ float Bs[32][68];
    __shared__ float cmS[16][68];
    __shared__ float ceS[16][68];
    int tid = threadIdx.x;
    int n0 = blockIdx.x * 64, m0 = blockIdx.y * 64;
    int cg = tid & 15, rg = tid >> 4;
    int r0 = rg * 4, c0 = cg * 4;
    int srow = tid & 63;
    int skq  = tid >> 6;
    float4 acc0 = make_float4(0.f,0.f,0.f,0.f);
    float4 acc1 = make_float4(0.f,0.f,0.f,0.f);
    float4 acc2 = make_float4(0.f,0.f,0.f,0.f);
    float4 acc3 = make_float4(0.f,0.f,0.f,0.f);

    for (int k0 = 0; k0 < 128; k0 += 32) {
        int ar = m0 + srow; ar = ar < LTOK ? ar : LTOK - 1;
        int br = n0 + srow; br = br < LTOK ? br : LTOK - 1;
        const float* ap = A + (size_t)ar * 128 + k0 + skq * 8;
        const float* bp = B + (size_t)br * 128 + k0 + skq * 8;
        float4 av0 = *(const float4*)(ap);
        float4 av1 = *(const float4*)(ap + 4);
        float4 bv0 = *(const float4*)(bp);
        float4 bv1 = *(const float4*)(bp + 4);
        int kk = skq * 8;
        As[kk+0][srow] = av0.x; As[kk+1][srow] = av0.y; As[kk+2][srow] = av0.z; As[kk+3][srow] = av0.w;
        As[kk+4][srow] = av1.x; As[kk+5][srow] = av1.y; As[kk+6][srow] = av1.z; As[kk+7][srow] = av1.w;
        Bs[kk+0][srow] = bv0.x; Bs[kk+1][srow] = bv0.y; Bs[kk+2][srow] = bv0.z; Bs[kk+3][srow] = bv0.w;
        Bs[kk+4][srow] = bv1.x; Bs[kk+5][srow] = bv1.y; Bs[kk+6][srow] = bv1.z; Bs[kk+7][srow] = bv1.w;
        __syncthreads();
        #pragma unroll
        for (int k = 0; k < 32; ++k) {
            float4 a = *(const float4*)(&As[k][r0]);
            float4 b = *(const float4*)(&Bs[k][c0]);
            acc0.x += a.x*b.x; acc0.y += a.x*b.y; acc0.z += a.x*b.z; acc0.w += a.x*b.w;
            acc1.x += a.y*b.x; acc1.y += a.y*b.y; acc1.z += a.y*b.z; acc1.w += a.y*b.w;
            acc2.x += a.z*b.x; acc2.y += a.z*b.y; acc2.z += a.z*b.z; acc2.w += a.z*b.w;
            acc3.x += a.w*b.x; acc3.y += a.w*b.y; acc3.z += a.w*b.z; acc3.w += a.w*b.w;
        }
        __syncthreads();
    }
    // scale by 10 and store (guarded)
    acc0.x *= 10.f; acc0.y *= 10.f; acc0.z *= 10.f; acc0.w *= 10.f;
    acc1.x *= 10.f; acc1.y *= 10.f; acc1.z *= 10.f; acc1.w *= 10.f;
    acc2.x *= 10.f; acc2.y *= 10.f; acc2.z *= 10.f; acc2.w *= 10.f;
    acc3.x *= 10.f; acc3.y *= 10.f; acc3.z *= 10.f; acc3.w *= 10.f;
    int gr = m0 + r0;
    bool colv = (n0 + c0) < LTOK;   // float4-aligned boundary (2080 % 4 == 0)
    if (colv) {
        if (gr + 0 < LTOK) *(float4*)(C + (size_t)(gr + 0) * LTOK + n0 + c0) = acc0;
        if (gr + 1 < LTOK) *(float4*)(C + (size_t)(gr + 1) * LTOK + n0 + c0) = acc1;
        if (gr + 2 < LTOK) *(float4*)(C + (size_t)(gr + 2) * LTOK + n0 + c0) = acc2;
        if (gr + 3 < LTOK) *(float4*)(C + (size_t)(gr + 3) * LTOK + n0 + c0) = acc3;
    }
    const float NEG = -1e30f;
    float v00 = colv ? acc0.x : NEG, v01 = colv ? acc0.y : NEG, v02 = colv ? acc0.z : NEG, v03 = colv ? acc0.w : NEG;
    float v10 = colv ? acc1.x : NEG, v11 = colv ? acc1.y : NEG, v12 = colv ? acc1.z : NEG, v13 = colv ? acc1.w : NEG;
    float v20 = colv ? acc2.x : NEG, v21 = colv ? acc2.y : NEG, v22 = colv ? acc2.z : NEG, v23 = colv ? acc2.w : NEG;
    float v30 = colv ? acc3.x : NEG, v31 = colv ? acc3.y : NEG, v32 = colv ? acc3.z : NEG, v33 = colv ? acc3.w : NEG;
    // ---- row partials: per-thread (max,sumexp) over 4 cols, merge over 16 cg-lanes ----
    #pragma unroll
    for (int i = 0; i < 4; ++i) {
        float a = (i==0)?v00:(i==1)?v10:(i==2)?v20:v30;
        float b = (i==0)?v01:(i==1)?v11:(i==2)?v21:v31;
        float c = (i==0)?v02:(i==1)?v12:(i==2)?v22:v32;
        float d = (i==0)?v03:(i==1)?v13:(i==2)?v23:v33;
        float m = fmaxf(fmaxf(a,b), fmaxf(c,d));
        float e = 0.f;
        if (m > NEG) e = __expf(a-m) + __expf(b-m) + __expf(c-m) + __expf(d-m);
        #pragma unroll
        for (int mm = 8; mm >= 1; mm >>= 1) {
            float m2 = __shfl_xor(m, mm, 16);
            float e2 = __shfl_xor(e, mm, 16);
            if (m2 > m) { e = e * __expf(m - m2) + e2; m = m2; }
            else if (m2 > NEG) { e += e2 * __expf(m2 - m); }
        }
        if (cg == 0 && gr + i < LTOK)
            prs[(size_t)blockIdx.x * LTOK + gr + i] = make_float2(m, e);
    }
    // ---- col partials: per-thread (max,sumexp) over its 4 valid rows, LDS-merge over 16 rgs ----
    bool rv0 = (gr + 0) < LTOK, rv1 = (gr + 1) < LTOK, rv2 = (gr + 2) < LTOK, rv3 = (gr + 3) < LTOK;
    #pragma unroll
    for (int j = 0; j < 4; ++j) {
        float a = rv0 ? ((j==0)?v00:(j==1)?v01:(j==2)?v02:v03) : NEG;
        float b = rv1 ? ((j==0)?v10:(j==1)?v11:(j==2)?v12:v13) : NEG;
        float c = rv2 ? ((j==0)?v20:(j==1)?v21:(j==2)?v22:v23) : NEG;
        float d = rv3 ? ((j==0)?v30:(j==1)?v31:(j==2)?v32:v33) : NEG;
        float m = fmaxf(fmaxf(a,b), fmaxf(c,d));
        float e = 0.f;
        if (m > NEG) {
            if (rv0) e += __expf(a-m);
            if (rv1) e += __expf(b-m);
            if (rv2) e += __expf(c-m);
            if (rv3) e += __expf(d-m);
        }
        cmS[rg][c0 + j] = m;
        ceS[rg][c0 + j] = e;
    }
    __syncthreads();
    if (tid < 64) {
        int col = tid;
        float m = cmS[0][col], e = ceS[0][col];
        #pragma unroll
        for (int k = 1; k < 16; ++k) {
            float m2 = cmS[k][col], e2 = ceS[k][col];
            if (m2 > m) { e = e * __expf(m - m2) + e2; m = m2; }
            else if (m2 > NEG) { e += e2 * __expf(m2 - m); }
        }
        if (n0 + col < LTOK)
            pcs[(size_t)blockIdx.y * LTOK + n0 + col] = make_float2(m, e);
    }
}

// ---------------- merge NST stat partials per row/col; store max + 1/sum ----------------
__global__ __launch_bounds__(256) void stats_combine_kernel(const float2* __restrict__ prs,
                                                            const float2* __restrict__ pcs,
                                                            float* __restrict__ rowmax,
                                                            float* __restrict__ rsinv,
                                                            float* __restrict__ colmax,
                                                            float* __restrict__ csinv)
{
    int id = blockIdx.x * 256 + threadIdx.x;
    if (id >= 2 * LTOK) return;
    const float2* p = (id < LTOK) ? (prs + id) : (pcs + (id - LTOK));
    float M = -1e30f;
    for (int i = 0; i < NST; ++i) M = fmaxf(M, p[(size_t)i * LTOK].x);
    float S = 0.f;
    for (int i = 0; i < NST; ++i) {
        float2 f = p[(size_t)i * LTOK];
        S += f.y * __expf(f.x - M);
    }
    if (id < LTOK) { rowmax[id] = M; rsinv[id] = 1.f / S; }
    else           { colmax[id - LTOK] = M; csinv[id - LTOK] = 1.f / S; }
}

// ---------------- P = exp(2S-rm-cm)*rsinv*csinv (in place) + argmax partials ----------------
__global__ __launch_bounds__(256) void dualp_argmax_kernel(float* __restrict__ S,
                                                           const float* __restrict__ rm,
                                                           const float* __restrict__ rsinv,
                                                           const float* __restrict__ cm,
                                                           const float* __restrict__ csinv,
                                                           float* __restrict__ prv,
                                                           int* __restrict__ pri,
                                                           float* __restrict__ pcv,
                                                           int* __restrict__ pci)
{
    __shared__ float cvS[8][32];
    __shared__ int   ciS[8][32];
    int tid = threadIdx.x;
    int n0 = blockIdx.x * 32, m0 = blockIdx.y * 32;
    int c = tid & 31, r8 = tid >> 5;
    int col = n0 + c;
    float cmv = cm[col], csv = csinv[col];
    float p[4];
    #pragma unroll
    for (int jj = 0; jj < 4; ++jj) {
        int row = m0 + 4 * r8 + jj;
        size_t o = (size_t)row * LTOK + col;
        float s = S[o];
        float pv = __expf(2.f * s - rm[row] - cmv) * (rsinv[row] * csv);
        S[o] = pv;
        p[jj] = pv;
    }
    #pragma unroll
    for (int jj = 0; jj < 4; ++jj) {
        float bv = p[jj]; int bi = col;
        #pragma unroll
        for (int mm = 16; mm >= 1; mm >>= 1) {
            float ov = __shfl_xor(bv, mm, 32);
            int   oi = __shfl_xor(bi, mm, 32);
            if (ov > bv || (ov == bv && oi < bi)) { bv = ov; bi = oi; }
        }
        if (c == 0) {
            prv[(size_t)blockIdx.x * LTOK + m0 + 4 * r8 + jj] = bv;
            pri[(size_t)blockIdx.x * LTOK + m0 + 4 * r8 + jj] = bi;
        }
    }
    float bv = p[0]; int bi = m0 + 4 * r8;
    #pragma unroll
    for (int jj = 1; jj < 4; ++jj)
        if (p[jj] > bv) { bv = p[jj]; bi = m0 + 4 * r8 + jj; }
    cvS[r8][c] = bv; ciS[r8][c] = bi;
    __syncthreads();
    if (r8 == 0) {
        #pragma unroll
        for (int k = 1; k < 8; ++k)
            if (cvS[k][c] > bv) { bv = cvS[k][c]; bi = ciS[k][c]; }
        pcv[(size_t)blockIdx.y * LTOK + col] = bv;
        pci[(size_t)blockIdx.y * LTOK + col] = bi;
    }
}

// ---------------- merge 65 argmax partials ----------------
__global__ __launch_bounds__(256) void argmax_combine_kernel(const float* __restrict__ prv,
                                                             const int* __restrict__ pri,
                                                             const float* __restrict__ pcv,
                                                             const int* __restrict__ pci,
                                                             int* __restrict__ idx0,
                                                             float* __restrict__ conf,
                                                             int* __restrict__ idx1)
{
    int id = blockIdx.x * 256 + threadIdx.x;
    if (id >= 2 * LTOK) return;
    if (id < LTOK) {
        float best = -1e30f; int bi = 0;
        for (int i = 0; i < 65; ++i) {
            float v = prv[(size_t)i * LTOK + id];
            if (v > best) { best = v; bi = pri[(size_t)i * LTOK + id]; }
        }
        idx0[id] = bi; conf[id] = best;
    } else {
        int colI = id - LTOK;
        float best = -1e30f; int bi = 0;
        for (int i = 0; i < 65; ++i) {
            float v = pcv[(size_t)i * LTOK + colI];
            if (v > best) { best = v; bi = pci[(size_t)i * LTOK + colI]; }
        }
        idx1[colI] = bi;
    }
}

// ---------------- MHA partial v2b (named scalars) ----------------
__global__ __launch_bounds__(256, 3) void mha_partial2_kernel(const float* __restrict__ qkvA,
                                                              const float* __restrict__ qkvB,
                                                              int cross,
                                                              float* __restrict__ part)
{
    __shared__ float Qs[QBLK][36];
    __shared__ float Ks[64][36];
    __shared__ float Vt[32][68];
    __shared__ float Ps[QBLK][68];
    int tid = threadIdx.x;
    int qb = blockIdx.x, ns = blockIdx.z;
    int img = blockIdx.y >> 2, h = blockIdx.y & 3;
    const float* qsrc  = img ? qkvB : qkvA;
    const float* kvsrc = cross ? (img ? qkvA : qkvB) : qsrc;
    int c4 = tid & 15;
    int rg = tid >> 4;
    const int r0 = rg * 4;
    const float sc = 0.17677669529663687f; // 1/sqrt(32)

    {
        int r = tid >> 2, d8 = (tid & 3) << 3;
        int qr = qb * QBLK + r; qr = qr < LTOK ? qr : (LTOK - 1);
        const float* src = qsrc + (size_t)qr * 384 + h * 32 + d8;
        *(float4*)(&Qs[r][d8])     = *(const float4*)(src);
        *(float4*)(&Qs[r][d8 + 4]) = *(const float4*)(src + 4);
    }
    float a00=0.f,a01=0.f,a10=0.f,a11=0.f,a20=0.f,a21=0.f,a30=0.f,a31=0.f;
    float l0=0.f,l1=0.f,l2=0.f,l3=0.f;
    __syncthreads();

    const int koff = 128 + h * 32, voff = 256 + h * 32;
    for (int t = ns; t < 33; t += NSPLIT2) {
        int j0 = t * 64;
        {
            int r = tid >> 3, d4 = (tid & 7) << 2;
            int j1 = j0 + r, j2 = j0 + r + 32;
            float4 k1 = *(const float4*)(kvsrc + (size_t)j1 * 384 + koff + d4);
            float4 v1 = *(const float4*)(kvsrc + (size_t)j1 * 384 + voff + d4);
            float4 k2 = make_float4(0.f, 0.f, 0.f, 0.f);
            float4 v2 = make_float4(0.f, 0.f, 0.f, 0.f);
            if (j2 < LTOK) {
                k2 = *(const float4*)(kvsrc + (size_t)j2 * 384 + koff + d4);
                v2 = *(const float4*)(kvsrc + (size_t)j2 * 384 + voff + d4);
            }
            *(float4*)(&Ks[r][d4])      = k1;
            *(float4*)(&Ks[r + 32][d4]) = k2;
            Vt[d4 + 0][r] = v1.x; Vt[d4 + 1][r] = v1.y; Vt[d4 + 2][r] = v1.z; Vt[d4 + 3][r] = v1.w;
            Vt[d4 + 0][r + 32] = v2.x; Vt[d4 + 1][r + 32] = v2.y; Vt[d4 + 2][r + 32] = v2.z; Vt[d4 + 3][r + 32] = v2.w;
        }
        __syncthreads();
        float s00=0.f,s01=0.f,s02=0.f,s03=0.f;
        float s10=0.f,s11=0.f,s12=0.f,s13=0.f;
        float s20=0.f,s21=0.f,s22=0.f,s23=0.f;
        float s30=0.f,s31=0.f,s32=0.f,s33=0.f;
        #pragma unroll
        for (int d4 = 0; d4 < 8; ++d4) {
            const int db = d4 << 2;
            float4 k0 = *(const float4*)(&Ks[c4][db]);
            float4 k1 = *(const float4*)(&Ks[c4 + 16][db]);
            float4 k2 = *(const float4*)(&Ks[c4 + 32][db]);
            float4 k3 = *(const float4*)(&Ks[c4 + 48][db]);
            float4 q0 = *(const float4*)(&Qs[r0 + 0][db]);
            float4 q1 = *(const float4*)(&Qs[r0 + 1][db]);
            float4 q2 = *(const float4*)(&Qs[r0 + 2][db]);
            float4 q3 = *(const float4*)(&Qs[r0 + 3][db]);
            s00 += DOT4(q0,k0); s01 += DOT4(q0,k1); s02 += DOT4(q0,k2); s03 += DOT4(q0,k3);
            s10 += DOT4(q1,k0); s11 += DOT4(q1,k1); s12 += DOT4(q1,k2); s13 += DOT4(q1,k3);
            s20 += DOT4(q2,k0); s21 += DOT4(q2,k1); s22 += DOT4(q2,k2); s23 += DOT4(q2,k3);
            s30 += DOT4(q3,k0); s31 += DOT4(q3,k1); s32 += DOT4(q3,k2); s33 += DOT4(q3,k3);
        }
        bool ok0 = (j0 + c4) < LTOK;
        bool ok1 = (j0 + 16 + c4) < LTOK;
        bool ok2 = (j0 + 32 + c4) < LTOK;
        bool ok3 = (j0 + 48 + c4) < LTOK;
        {
            float p0 = ok0 ? __expf(s00 * sc) : 0.f;
            float p1 = ok1 ? __expf(s01 * sc) : 0.f;
            float p2 = ok2 ? __expf(s02 * sc) : 0.f;
            float p3 = ok3 ? __expf(s03 * sc) : 0.f;
            l0 += p0 + p1 + p2 + p3;
            Ps[r0 + 0][c4] = p0; Ps[r0 + 0][c4 + 16] = p1; Ps[r0 + 0][c4 + 32] = p2; Ps[r0 + 0][c4 + 48] = p3;
        }
        {
            float p0 = ok0 ? __expf(s10 * sc) : 0.f;
            float p1 = ok1 ? __expf(s11 * sc) : 0.f;
            float p2 = ok2 ? __expf(s12 * sc) : 0.f;
            float p3 = ok3 ? __expf(s13 * sc) : 0.f;
            l1 += p0 + p1 + p2 + p3;
            Ps[r0 + 1][c4] = p0; Ps[r0 + 1][c4 + 16] = p1; Ps[r0 + 1][c4 + 32] = p2; Ps[r0 + 1][c4 + 48] = p3;
        }
        {
            float p0 = ok0 ? __expf(s20 * sc) : 0.f;
            float p1 = ok1 ? __expf(s21 * sc) : 0.f;
            float p2 = ok2 ? __expf(s22 * sc) : 0.f;
            float p3 = ok3 ? __expf(s23 * sc) : 0.f;
            l2 += p0 + p1 + p2 + p3;
            Ps[r0 + 2][c4] = p0; Ps[r0 + 2][c4 + 16] = p1; Ps[r0 + 2][c4 + 32] = p2; Ps[r0 + 2][c4 + 48] = p3;
        }
        {
            float p0 = ok0 ? __expf(s30 * sc) : 0.f;
            float p1 = ok1 ? __expf(s31 * sc) : 0.f;
            float p2 = ok2 ? __expf(s32 * sc) : 0.f;
            float p3 = ok3 ? __expf(s33 * sc) : 0.f;
            l3 += p0 + p1 + p2 + p3;
            Ps[r0 + 3][c4] = p0; Ps[r0 + 3][c4 + 16] = p1; Ps[r0 + 3][c4 + 32] = p2; Ps[r0 + 3][c4 + 48] = p3;
        }
        __syncthreads();
        #pragma unroll
        for (int j4 = 0; j4 < 16; ++j4) {
            const int jb = j4 << 2;
            float4 v0 = *(const float4*)(&Vt[c4][jb]);
            float4 v1 = *(const float4*)(&Vt[c4 + 16][jb]);
            float4 pq0 = *(const float4*)(&Ps[r0 + 0][jb]);
            float4 pq1 = *(const float4*)(&Ps[r0 + 1][jb]);
            float4 pq2 = *(const float4*)(&Ps[r0 + 2][jb]);
            float4 pq3 = *(const float4*)(&Ps[r0 + 3][jb]);
            a00 += DOT4(pq0,v0); a01 += DOT4(pq0,v1);
            a10 += DOT4(pq1,v0); a11 += DOT4(pq1,v1);
            a20 += DOT4(pq2,v0); a21 += DOT4(pq2,v1);
            a30 += DOT4(pq3,v0); a31 += DOT4(pq3,v1);
        }
        __syncthreads();
    }
    float* pb = part + (size_t)((((size_t)img * NQB + qb) * NH + h) * NSPLIT2 + ns) * PSTRIDE2;
    pb[(r0 + 0) * 32 + c4]      = a00;
    pb[(r0 + 0) * 32 + c4 + 16] = a01;
    pb[(r0 + 1) * 32 + c4]      = a10;
    pb[(r0 + 1) * 32 + c4 + 16] = a11;
    pb[(r0 + 2) * 32 + c4]      = a20;
    pb[(r0 + 2) * 32 + c4 + 16] = a21;
    pb[(r0 + 3) * 32 + c4]      = a30;
    pb[(r0 + 3) * 32 + c4 + 16] = a31;
    #pragma unroll
    for (int mm = 8; mm >= 1; mm >>= 1) {
        l0 += __shfl_xor(l0, mm, 16);
        l1 += __shfl_xor(l1, mm, 16);
        l2 += __shfl_xor(l2, mm, 16);
        l3 += __shfl_xor(l3, mm, 16);
    }
    if (c4 == 0) {
        pb[2048 + r0 + 0] = l0;
        pb[2048 + r0 + 1] = l1;
        pb[2048 + r0 + 2] = l2;
        pb[2048 + r0 + 3] = l3;
    }
}

// ---------------- MHA combine v2: grid (33, 8) ----------------
__global__ __launch_bounds__(256) void mha_combine2_kernel(const float* __restrict__ part,
                                                           float* __restrict__ out0,
                                                           float* __restrict__ out1)
{
    int tid = threadIdx.x;
    int qb = blockIdx.x;
    int img = blockIdx.y >> 2, h = blockIdx.y & 3;
    float* out = img ? out1 : out0;
    int c = tid & 31, rg8 = tid >> 5;
    const float* pb = part + (size_t)(((size_t)img * NQB + qb) * NH + h) * NSPLIT2 * PSTRIDE2;
    #pragma unroll
    for (int jj = 0; jj < 8; ++jj) {
        int row = rg8 * 8 + jj;
        int qrow = qb * QBLK + row;
        if (qrow >= LTOK) continue;
        float num = 0.f, den = 0.f;
        #pragma unroll
        for (int ns = 0; ns < NSPLIT2; ++ns) {
            num += pb[ns * PSTRIDE2 + row * 32 + c];
            den += pb[ns * PSTRIDE2 + 2048 + row];
        }
        out[(size_t)qrow * DIM + h * 32 + c] = num / den;
    }
}

// ---------------- residual add + LayerNorm (in place), batched ----------------
__global__ __launch_bounds__(256) void addln_b_kernel(float* __restrict__ f0,
                                                      float* __restrict__ f1,
                                                      const float* __restrict__ t0,
                                                      const float* __restrict__ t1,
                                                      const float* __restrict__ g,
                                                      const float* __restrict__ b)
{
    float* f = blockIdx.y ? f1 : f0;
    const float* t = blockIdx.y ? t1 : t0;
    int row = blockIdx.x * 4 + (threadIdx.x >> 6);
    int lane = threadIdx.x & 63;
    size_t base = (size_t)row * DIM;
    float x0 = f[base + lane] + t[base + lane];
    float x1 = f[base + lane + 64] + t[base + lane + 64];
    float s = x0 + x1;
    #pragma unroll
    for (int mm = 32; mm >= 1; mm >>= 1) s += __shfl_xor(s, mm, 64);
    float mean = s * (1.f / 128.f);
    float d0 = x0 - mean, d1 = x1 - mean;
    float v = d0 * d0 + d1 * d1;
    #pragma unroll
    for (int mm = 32; mm >= 1; mm >>= 1) v += __shfl_xor(v, mm, 64);
    float rstd = rsqrtf(v * (1.f / 128.f) + 1e-5f);
    f[base + lane]      = d0 * rstd * g[lane] + b[lane];
    f[base + lane + 64] = d1 * rstd * g[lane + 64] + b[lane + 64];
}

// ---------------- L2-normalize rows, batched ----------------
__global__ __launch_bounds__(256) void normrows_b_kernel(const float* __restrict__ i0,
                                                         const float* __restrict__ i1,
                                                         float* __restrict__ o0,
                                                         float* __restrict__ o1)
{
    const float* f = blockIdx.y ? i1 : i0;
    float* o = blockIdx.y ? o1 : o0;
    int row = blockIdx.x * 4 + (threadIdx.x >> 6);
    int lane = threadIdx.x & 63;
    size_t base = (size_t)row * DIM;
    float x0 = f[base + lane], x1 = f[base + lane + 64];
    float v = x0 * x0 + x1 * x1;
    #pragma unroll
    for (int mm = 32; mm >= 1; mm >>= 1) v += __shfl_xor(v, mm, 64);
    float inv = 1.f / fmaxf(sqrtf(v), 1e-12f);
    o[base + lane] = x0 * inv;
    o[base + lane + 64] = x1 * inv;
}

// ---------------- match outputs: valid, conf, pt0 ----------------
__global__ __launch_bounds__(256) void match_kernel(const int* __restrict__ idx0,
                                                    const int* __restrict__ idx1,
                                                    const float* __restrict__ conf,
                                                    float* __restrict__ out_valid,
                                                    float* __restrict__ out_conf,
                                                    float* __restrict__ out_pt0)
{
    int i = blockIdx.x * 256 + threadIdx.x;
    if (i >= LTOK) return;
    int j = idx0[i];
    bool valid = (idx1[j] == i) && (conf[i] > 0.2f);
    out_valid[i] = valid ? 1.f : 0.f;
    out_conf[i] = conf[i];
    out_pt0[2 * i]     = (float)(i % W0C) * 8.f + 4.f;
    out_pt0[2 * i + 1] = (float)(i / W0C) * 8.f + 4.f;
}

// ---------------- fine projection, batched ----------------
__global__ __launch_bounds__(256) void fine_proj_b_kernel(const float* __restrict__ fin0,
                                                          const float* __restrict__ fin1,
                                                          const float* __restrict__ w,
                                                          const float* __restrict__ b,
                                                          float* __restrict__ fout0,
                                                          float* __restrict__ fout1)
{
    const float* fin = blockIdx.y ? fin1 : fin0;
    float* fout = blockIdx.y ? fout1 : fout0;
    __shared__ float ws_[32][32];
    __shared__ float bs[32];
    int t = threadIdx.x;
    #pragma unroll
    for (int e = 0; e < 4; ++e) { int l = t + e * 256; ws_[l >> 5][l & 31] = w[l]; }
    if (t < 32) bs[t] = b[t];
    __syncthreads();
    int p = blockIdx.x * 256 + t;
    if (p >= NPIX) return;
    float x[32];
    #pragma unroll
    for (int cc = 0; cc < 32; ++cc) x[cc] = fin[(size_t)cc * NPIX + p];
    #pragma unroll
    for (int o = 0; o < 32; ++o) {
        float a = bs[o];
        #pragma unroll
        for (int cc = 0; cc < 32; ++cc) a += ws_[o][cc] * x[cc];
        fout[(size_t)o * NPIX + p] = a;
    }
}

// ---------------- fine match ----------------
__global__ __launch_bounds__(64) void fine_match_kernel(const int* __restrict__ idx0,
                                                        const float* __restrict__ f0p,
                                                        const float* __restrict__ f1p,
                                                        float* __restrict__ out_pt1)
{
    int i = blockIdx.x;
    int l = threadIdx.x;
    int j = idx0[i];
    int m0x = i % W0C, m0y = i / W0C;
    int m1x = j % W0C, m1y = j / W0C;
    int c0x = m0x * 4, c0y = m0y * 4, c1x = m1x * 4, c1y = m1y * 4;
    bool inb = (c0x - 2 >= 0) && (c0x + 2 < WFI) && (c0y - 2 >= 0) && (c0y + 2 < HFI)
            && (c1x - 2 >= 0) && (c1x + 2 < WFI) && (c1y - 2 >= 0) && (c1y + 2 < HFI);
    int cy0 = min(max(c0y, 2), HFI - 3), cx0 = min(max(c0x, 2), WFI - 3);
    int cy1 = min(max(c1y, 2), HFI - 3), cx1 = min(max(c1x, 2), WFI - 3);
    int dy = l / 5 - 2, dx = l % 5 - 2;
    float corr = -1e30f;
    if (l < 25) {
        float a = 0.f;
        int p0 = cy0 * WFI + cx0;
        int p1 = (cy1 + dy) * WFI + (cx1 + dx);
        #pragma unroll
        for (int cc = 0; cc < 32; ++cc)
            a += f0p[(size_t)cc * NPIX + p0] * f1p[(size_t)cc * NPIX + p1];
        corr = a;
    }
    float mx = corr;
    #pragma unroll
    for (int mm = 32; mm >= 1; mm >>= 1) mx = fmaxf(mx, __shfl_xor(mx, mm, 64));
    float p = (l < 25) ? expf(corr - mx) : 0.f;
    float s = p, sx = p * (float)dx, sy = p * (float)dy;
    #pragma unroll
    for (int mm = 32; mm >= 1; mm >>= 1) {
        s  += __shfl_xor(s, mm, 64);
        sx += __shfl_xor(sx, mm, 64);
        sy += __shfl_xor(sy, mm, 64);
    }
    if (l == 0) {
        float offx = sx / s, offy = sy / s;
        float px = (float)m1x * 8.f + 4.f;
        float py = (float)m1y * 8.f + 4.f;
        if (inb) { px += offx * 2.f; py += offy * 2.f; }
        out_pt1[2 * i]     = px;
        out_pt1[2 * i + 1] = py;
    }
}

// ---------------- host launch ----------------
extern "C" void kernel_launch(void* const* d_in, const int* in_sizes, int n_in,
                              void* d_out, int out_size, void* d_ws, size_t ws_size,
                              hipStream_t stream) {
    (void)in_sizes; (void)n_in; (void)out_size; (void)ws_size;
    const float* coarse0 = (const float*)d_in[0];
    const float* coarse1 = (const float*)d_in[1];
    const float* fine0   = (const float*)d_in[2];
    const float* fine1   = (const float*)d_in[3];
    const float* sa_in_w  = (const float*)d_in[4];
    const float* sa_in_b  = (const float*)d_in[5];
    const float* sa_out_w = (const float*)d_in[6];
    const float* sa_out_b = (const float*)d_in[7];
    const float* ca_in_w  = (const float*)d_in[8];
    const float* ca_in_b  = (const float*)d_in[9];
    const float* ca_out_w = (const float*)d_in[10];
    const float* ca_out_b = (const float*)d_in[11];
    const float* sn_g = (const float*)d_in[12];
    const float* sn_b = (const float*)d_in[13];
    const float* cn_g = (const float*)d_in[14];
    const float* cn_b = (const float*)d_in[15];
    const float* ffn_w1 = (const float*)d_in[16];
    const float* ffn_b1 = (const float*)d_in[17];
    const float* ffn_w2 = (const float*)d_in[18];
    const float* ffn_b2 = (const float*)d_in[19];
    const float* fn_g = (const float*)d_in[20];
    const float* fn_b = (const float*)d_in[21];
    const float* proj_w = (const float*)d_in[22];
    const float* proj_b = (const float*)d_in[23];

    float* w = (float*)d_ws;
    float* f0   = w; w += (size_t)LTOK * DIM;
    float* f1   = w; w += (size_t)LTOK * DIM;
    float* qkv0 = w; w += (size_t)LTOK * 384;
    float* qkv1 = w; w += (size_t)LTOK * 384;
    float* att0 = w; w += (size_t)LTOK * DIM;
    float* att1 = w; w += (size_t)LTOK * DIM;
    float* tmp0 = w; w += (size_t)LTOK * DIM;
    float* tmp1 = w; w += (size_t)LTOK * DIM;
    float* f0n  = w; w += (size_t)LTOK * DIM;
    float* f1n  = w; w += (size_t)LTOK * DIM;
    float* R1   = w; w += (size_t)3345408;
    float* rowmax = w; w += LTOK;
    float* rsinv  = w; w += LTOK;
    float* colmax = w; w += LTOK;
    float* csinv  = w; w += LTOK;
    float* conf   = w; w += LTOK;
    int* idx0 = (int*)w; w += LTOK;
    int* idx1 = (int*)w; w += LTOK;

    float* part = R1;
    float* hid0 = R1;
    float* hid1 = R1 + (size_t)LTOK * 256;
    float* f0p  = R1;
    float* f1p  = R1 + (size_t)CFCH * NPIX;

    float2* prs = (float2*)qkv0;                        // NST*LTOK float2
    float2* pcs = (float2*)(qkv0 + 2 * NST * LTOK);
    float*  prv = qkv1;
    int*    pri = (int*)(qkv1 + 65 * LTOK);
    float*  pcv = qkv1 + 2 * 65 * LTOK;
    int*    pci = (int*)(qkv1 + 3 * 65 * LTOK);

    float* Pout = (float*)d_out;
    float* out_valid = Pout + (size_t)LTOK * LTOK;
    float* out_conf  = out_valid + LTOK;
    float* out_pt0   = out_conf + LTOK;
    float* out_pt1   = out_pt0 + 2 * LTOK;

    dim3 b256(256);
    dim3 gMHA(NQB, 8, NSPLIT2);
    dim3 gCMB(NQB, 8);
    dim3 gLN(520, 2);
    transpose_b_kernel<<<dim3(65, 4, 2), b256, 0, stream>>>(coarse0, coarse1, f0, f1);

    for (int i = 0; i < 2; ++i) {
        const float* saw = sa_in_w + (size_t)i * 384 * 128;
        const float* sab = sa_in_b + (size_t)i * 384;
        const float* sow = sa_out_w + (size_t)i * 128 * 128;
        const float* sob = sa_out_b + (size_t)i * 128;
        const float* caw = ca_in_w + (size_t)i * 384 * 128;
        const float* cab = ca_in_b + (size_t)i * 384;
        const float* cow = ca_out_w + (size_t)i * 128 * 128;
        const float* cob = ca_out_b + (size_t)i * 128;
        const float* w1 = ffn_w1 + (size_t)i * 256 * 128;
        const float* b1 = ffn_b1 + (size_t)i * 256;
        const float* w2 = ffn_w2 + (size_t)i * 128 * 256;
        const float* b2 = ffn_b2 + (size_t)i * 128;

        // ---- self attention ----
        gemm64_nt_b2_kernel<<<dim3(6, 33, 2), b256, 0, stream>>>(f0, f1, 128, saw, 128, qkv0, qkv1, 384, 128, sab, 0, LTOK);
        mha_partial2_kernel<<<gMHA, b256, 0, stream>>>(qkv0, qkv1, 0, part);
        mha_combine2_kernel<<<gCMB, b256, 0, stream>>>(part, att0, att1);
        gemm64_nt_b2_kernel<<<dim3(2, 33, 2), b256, 0, stream>>>(att0, att1, 128, sow, 128, tmp0, tmp1, 128, 128, sob, 0, LTOK);
        addln_b_kernel<<<gLN, b256, 0, stream>>>(f0, f1, tmp0, tmp1, sn_g + (size_t)i * 128, sn_b + (size_t)i * 128);

        // ---- cross attention ----
        gemm64_nt_b2_kernel<<<dim3(6, 33, 2), b256, 0, stream>>>(f0, f1, 128, caw, 128, qkv0, qkv1, 384, 128, cab, 0, LTOK);
        mha_partial2_kernel<<<gMHA, b256, 0, stream>>>(qkv0, qkv1, 1, part);
        mha_combine2_kernel<<<gCMB, b256, 0, stream>>>(part, att0, att1);
        gemm64_nt_b2_kernel<<<dim3(2, 33, 2), b256, 0, stream>>>(att0, att1, 128, cow, 128, tmp0, tmp1, 128, 128, cob, 0, LTOK);
        addln_b_kernel<<<gLN, b256, 0, stream>>>(f0, f1, tmp0, tmp1, cn_g + (size_t)i * 128, cn_b + (size_t)i * 128);

        // ---- FFN ----
        gemm64_nt_b2_kernel<<<dim3(4, 33, 2), b256, 0, stream>>>(f0, f1, 128, w1, 128, hid0, hid1, 256, 128, b1, 1, LTOK);
        gemm64_nt_b2_kernel<<<dim3(2, 33, 2), b256, 0, stream>>>(hid0, hid1, 256, w2, 256, tmp0, tmp1, 128, 256, b2, 0, LTOK);
        addln_b_kernel<<<gLN, b256, 0, stream>>>(f0, f1, tmp0, tmp1, fn_g + (size_t)i * 128, fn_b + (size_t)i * 128);
    }

    // ---- matching (2 matrix passes total) ----
    normrows_b_kernel<<<gLN, b256, 0, stream>>>(f0, f1, f0n, f1n);
    gemm_score64_kernel<<<dim3(NST, NST), b256, 0, stream>>>(f0n, f1n, Pout, prs, pcs);
    stats_combine_kernel<<<17, b256, 0, stream>>>(prs, pcs, rowmax, rsinv, colmax, csinv);
    dualp_argmax_kernel<<<dim3(65, 65), b256, 0, stream>>>(Pout, rowmax, rsinv, colmax, csinv,
                                                           prv, pri, pcv, pci);
    argmax_combine_kernel<<<17, b256, 0, stream>>>(prv, pri, pcv, pci, idx0, conf, idx1);
    match_kernel<<<9, b256, 0, stream>>>(idx0, idx1, conf, out_valid, out_conf, out_pt0);

    // ---- fine refinement ----
    fine_proj_b_kernel<<<dim3(130, 2), b256, 0, stream>>>(fine0, fine1, proj_w, proj_b, f0p, f1p);
    fine_match_kernel<<<LTOK, dim3(64), 0, stream>>>(idx0, f0p, f1p, out_pt1);
}